// Round 8
// baseline (162.548 us; speedup 1.0000x reference)
//
#include <hip/hip_runtime.h>
#include <cstddef>

// Sizes (fixed per reference): B=8192, D=784, H=256, E=32, K=512
#define NB 8192
#define ND 784
#define NH 256
#define NE 32
#define NK 512
#define ALPHA_F 1000.0f

typedef _Float16 h8 __attribute__((ext_vector_type(8)));
typedef float f32x4 __attribute__((ext_vector_type(4)));

// ---------------------------------------------------------------------------
// prep4: W [K][N] fp32 -> WT hi/lo fp16 planes [N][K], via 32x32 LDS tiles.
// ---------------------------------------------------------------------------
#define TW1 25
#define TN1 8
#define NBW1 200        // W1 784x256
#define TW4 8
#define TN4 25
#define NBW4 200        // W4 256x784
#define NBW2 8          // W2 256x32
#define NBW3 8          // W3 32x256

__global__ __launch_bounds__(256)
void prep4_kernel(const float* __restrict__ W1, _Float16* __restrict__ w1thi,
                  _Float16* __restrict__ w1tlo,
                  const float* __restrict__ W4, _Float16* __restrict__ w4thi,
                  _Float16* __restrict__ w4tlo,
                  const float* __restrict__ W2, _Float16* __restrict__ w2thi,
                  _Float16* __restrict__ w2tlo,
                  const float* __restrict__ W3, _Float16* __restrict__ w3thi,
                  _Float16* __restrict__ w3tlo) {
    __shared__ float tile[32][33];
    const int b   = blockIdx.x;
    const int tid = threadIdx.x;

    const float* W; _Float16 *hi, *lo; int K, N, kt, nt;
    if (b < NBW1) {
        W = W1; hi = w1thi; lo = w1tlo; K = ND; N = NH;
        kt = b % TW1; nt = b / TW1;
    } else if (b < NBW1 + NBW4) {
        const int bb = b - NBW1;
        W = W4; hi = w4thi; lo = w4tlo; K = NH; N = ND;
        kt = bb % TW4; nt = bb / TW4;
    } else if (b < NBW1 + NBW4 + NBW2) {
        W = W2; hi = w2thi; lo = w2tlo; K = NH; N = NE;
        kt = b - (NBW1 + NBW4); nt = 0;
    } else {
        W = W3; hi = w3thi; lo = w3tlo; K = NE; N = NH;
        kt = 0; nt = b - (NBW1 + NBW4 + NBW2);
    }
    const int k0 = kt * 32, n0 = nt * 32;
    const int row = tid >> 3, c4 = (tid & 7) * 4;
    #pragma unroll
    for (int j = 0; j < 4; ++j) {
        const int k = k0 + row, n = n0 + c4 + j;
        tile[row][c4 + j] = (k < K && n < N) ? W[(size_t)k * N + n] : 0.f;
    }
    __syncthreads();
    const int n = n0 + row;
    if (n < N) {
        #pragma unroll
        for (int j = 0; j < 4; ++j) {
            const int k = k0 + c4 + j;
            if (k < K) {
                float w = tile[c4 + j][row];
                _Float16 hh = (_Float16)w;
                float r = w - (float)hh;
                hi[(size_t)n * K + k] = hh;
                lo[(size_t)n * K + k] = (_Float16)(r * 2048.0f);
            }
        }
    }
}

// ---------------------------------------------------------------------------
// MEGA v4 = v3 + phase-4 4-slot LDS pairing (2 K-steps per barrier interval:
// readers use slots {2i,2i+1}&3, commits write {2i+2,2i+3}&3 — disjoint, so
// one barrier covers both; 56 -> 28 intervals, 6 MFMA/wave/interval) and
// phase-5 exp reuse (read exps back from tr instead of recomputing expf).
// 1024 threads (16 waves), LDS 135936B -> 1 block/CU.
// ---------------------------------------------------------------------------
#define HSTR 264

__global__ __launch_bounds__(1024, 4)
void mega_kernel(const float* __restrict__ x, const float* __restrict__ reps,
                 const _Float16* __restrict__ w1thi, const _Float16* __restrict__ w1tlo,
                 const _Float16* __restrict__ w2thi, const _Float16* __restrict__ w2tlo,
                 const _Float16* __restrict__ w3thi, const _Float16* __restrict__ w3tlo,
                 const _Float16* __restrict__ w4thi, const _Float16* __restrict__ w4tlo,
                 const float* __restrict__ b1, const float* __restrict__ b2,
                 const float* __restrict__ b3, const float* __restrict__ b4,
                 float* __restrict__ emb_g, float* __restrict__ recon_g,
                 float* __restrict__ dist_g, float* __restrict__ wout_g) {
    // [0,81920)       R_B: ph1 sB dbuf | ph2 W2 | ph3 W3 | ph4 sB 4-slot |
    //                      ph5 tr0 [16][520] @0 + tr1 @33280
    // [81920,92160)   sA dbuf (ph1)
    // [92160,125952)  h planes (ph1-2) / h2 planes (ph3-4)
    // [125952,130560) es fp32 [32][36]
    // [130560,135680) emb planes [32][40] x2
    // [135680,135936) rmin[32], rinv[32]
    __shared__ __align__(16) unsigned char lds[135936];
    _Float16* R0h  = (_Float16*)lds;
    _Float16* sA   = (_Float16*)(lds + 81920);
    _Float16* hP   = (_Float16*)(lds + 92160);
    float*    es   = (float*)(lds + 125952);
    _Float16* eh   = (_Float16*)(lds + 130560);
    _Float16* el   = (_Float16*)(lds + 133120);
    float*    rmin = (float*)(lds + 135680);
    float*    rinv = (float*)(lds + 135808);

    const int tid  = threadIdx.x;
    const int lane = tid & 63;
    const int wv   = tid >> 6;          // 0..15
    const int li   = lane & 15;
    const int kq   = (lane >> 4) * 8;
    const int quad = lane >> 4;
    const int r0   = blockIdx.x * 32;

    const float c1 = 1.0f / 2048.0f;
    const float c2 = c1 * c1;

    // ---------------- phase 1: h planes = split(relu(x @ W1 + b1)) ----------
    {
        _Float16* sBhi = R0h;                   // [2][256*40]
        _Float16* sBlo = R0h + 2 * 256 * 40;
        _Float16* sAhi = sA;                    // [2][32*40]
        _Float16* sAlo = sA + 2 * 32 * 40;
        const int aro  = tid >> 2;              // A: tid<128 -> rows 0..31
        const int ak   = (tid & 3) * 8;
        const int brow = tid >> 2;              // B: 0..255
        const int bk   = (tid & 3) * 8;
        const float*    pA  = x + (size_t)(r0 + aro) * ND;
        const _Float16* pBh = w1thi + (size_t)brow * ND;
        const _Float16* pBl = w1tlo + (size_t)brow * ND;

        float araw[8];
        h8 rbh, rbl;

        auto pf = [&](int s) {
            if (tid < 128) {
                const int k = s * 32 + ak;
                if (k + 8 <= ND) {
                    f32x4 v0 = *(const f32x4*)(pA + k);
                    f32x4 v1 = *(const f32x4*)(pA + k + 4);
                    #pragma unroll
                    for (int j = 0; j < 4; ++j) {
                        araw[j] = v0[j]; araw[4 + j] = v1[j];
                    }
                } else {
                    #pragma unroll
                    for (int j = 0; j < 8; ++j) araw[j] = 0.f;
                }
            }
            const int kb = s * 32 + bk;
            rbh = (kb + 8 <= ND) ? *(const h8*)(pBh + kb) : (h8){};
            rbl = (kb + 8 <= ND) ? *(const h8*)(pBl + kb) : (h8){};
        };
        auto cm = [&](int buf) {
            if (tid < 128) {
                h8 hi, lo;
                #pragma unroll
                for (int j = 0; j < 8; ++j) {
                    float v = araw[j];
                    _Float16 hh = (_Float16)v;
                    hi[j] = hh;
                    lo[j] = (_Float16)((v - (float)hh) * 2048.0f);
                }
                *(h8*)&sAhi[buf * 32 * 40 + aro * 40 + ak] = hi;
                *(h8*)&sAlo[buf * 32 * 40 + aro * 40 + ak] = lo;
            }
            *(h8*)&sBhi[buf * 256 * 40 + brow * 40 + bk] = rbh;
            *(h8*)&sBlo[buf * 256 * 40 + brow * 40 + bk] = rbl;
        };

        pf(0); cm(0); pf(1);
        __syncthreads();

        f32x4 a0[2] = {}, a1[2] = {}, a2[2] = {};
        for (int s = 0; s < 25; ++s) {
            const int buf = s & 1;
            h8 fah[2], fal[2];
            #pragma unroll
            for (int mt = 0; mt < 2; ++mt) {
                const int ao = buf * 32 * 40 + (mt * 16 + li) * 40 + kq;
                fah[mt] = *(const h8*)&sAhi[ao];
                fal[mt] = *(const h8*)&sAlo[ao];
            }
            const int bo = buf * 256 * 40 + (wv * 16 + li) * 40 + kq;
            h8 fbh = *(const h8*)&sBhi[bo];
            h8 fbl = *(const h8*)&sBlo[bo];
            #pragma unroll
            for (int mt = 0; mt < 2; ++mt) {
                a0[mt] = __builtin_amdgcn_mfma_f32_16x16x32_f16(fah[mt], fbh, a0[mt], 0, 0, 0);
                a1[mt] = __builtin_amdgcn_mfma_f32_16x16x32_f16(fah[mt], fbl, a1[mt], 0, 0, 0);
                a1[mt] = __builtin_amdgcn_mfma_f32_16x16x32_f16(fal[mt], fbh, a1[mt], 0, 0, 0);
                a2[mt] = __builtin_amdgcn_mfma_f32_16x16x32_f16(fal[mt], fbl, a2[mt], 0, 0, 0);
            }
            if (s + 1 < 25) { cm((s + 1) & 1); if (s + 2 < 25) pf(s + 2); }
            __syncthreads();
        }
        // epilogue -> h planes [32][264]
        _Float16* hhi = hP;
        _Float16* hlo = hP + 32 * HSTR;
        const int n = wv * 16 + li;
        const float bv = b1[n];
        #pragma unroll
        for (int mt = 0; mt < 2; ++mt)
            #pragma unroll
            for (int r = 0; r < 4; ++r) {
                const int m = mt * 16 + quad * 4 + r;
                float v = a0[mt][r] + c1 * a1[mt][r] + c2 * a2[mt][r] + bv;
                v = fmaxf(v, 0.f);
                _Float16 t = (_Float16)v;
                hhi[m * HSTR + n] = t;
                hlo[m * HSTR + n] = (_Float16)((v - (float)t) * 2048.0f);
            }
    }
    __syncthreads();

    // ---------------- phase 2: emb = h @ W2 + b2 ----------------------------
    {   // stage W2T planes [32][256] -> LDS [32][264]
        _Float16* w2h = R0h;
        _Float16* w2l = R0h + 32 * HSTR;
        const int row = tid >> 5, off = (tid & 31) * 8;
        *(h8*)&w2h[row * HSTR + off] = *(const h8*)(w2thi + row * 256 + off);
        *(h8*)&w2l[row * HSTR + off] = *(const h8*)(w2tlo + row * 256 + off);
    }
    __syncthreads();
    if (wv < 4) {
        const int mt = wv >> 1, nt = wv & 1;
        _Float16* hhi = hP;
        _Float16* hlo = hP + 32 * HSTR;
        _Float16* w2h = R0h;
        _Float16* w2l = R0h + 32 * HSTR;
        f32x4 e0 = {}, e1 = {}, e2 = {};
        #pragma unroll
        for (int ks = 0; ks < 8; ++ks) {
            const int k = ks * 32 + kq;
            h8 ah = *(const h8*)&hhi[(mt * 16 + li) * HSTR + k];
            h8 al = *(const h8*)&hlo[(mt * 16 + li) * HSTR + k];
            h8 bh = *(const h8*)&w2h[(nt * 16 + li) * HSTR + k];
            h8 bl = *(const h8*)&w2l[(nt * 16 + li) * HSTR + k];
            e0 = __builtin_amdgcn_mfma_f32_16x16x32_f16(ah, bh, e0, 0, 0, 0);
            e1 = __builtin_amdgcn_mfma_f32_16x16x32_f16(ah, bl, e1, 0, 0, 0);
            e1 = __builtin_amdgcn_mfma_f32_16x16x32_f16(al, bh, e1, 0, 0, 0);
            e2 = __builtin_amdgcn_mfma_f32_16x16x32_f16(al, bl, e2, 0, 0, 0);
        }
        const int col = nt * 16 + li;
        const float bv = b2[col];
        #pragma unroll
        for (int r = 0; r < 4; ++r) {
            const int m = mt * 16 + quad * 4 + r;
            float v = e0[r] + c1 * e1[r] + c2 * e2[r] + bv;
            es[m * 36 + col] = v;
            _Float16 t = (_Float16)v;
            eh[m * 40 + col] = t;
            el[m * 40 + col] = (_Float16)((v - (float)t) * 2048.0f);
            emb_g[(size_t)(r0 + m) * NE + col] = v;
        }
    }
    __syncthreads();

    // ---------------- phase 3: h2 planes = split(relu(emb @ W3 + b3)) -------
    {   // stage W3T planes [256][32] -> LDS [256][40]
        _Float16* w3h = R0h;
        _Float16* w3l = R0h + 256 * 40;
        const int row = tid >> 2, off = (tid & 3) * 8;
        *(h8*)&w3h[row * 40 + off] = *(const h8*)(w3thi + row * 32 + off);
        *(h8*)&w3l[row * 40 + off] = *(const h8*)(w3tlo + row * 32 + off);
    }
    __syncthreads();
    {
        _Float16* w3h  = R0h;
        _Float16* w3l  = R0h + 256 * 40;
        _Float16* h2h  = hP;                    // overlays h (dead after ph2)
        _Float16* h2l  = hP + 32 * HSTR;
        h8 ah[2], al[2];
        #pragma unroll
        for (int mt = 0; mt < 2; ++mt) {
            ah[mt] = *(const h8*)&eh[(mt * 16 + li) * 40 + kq];
            al[mt] = *(const h8*)&el[(mt * 16 + li) * 40 + kq];
        }
        const int col = wv * 16 + li;
        h8 bh = *(const h8*)&w3h[col * 40 + kq];
        h8 bl = *(const h8*)&w3l[col * 40 + kq];
        const float bv = b3[col];
        #pragma unroll
        for (int mt = 0; mt < 2; ++mt) {
            f32x4 q0 = {}, q1 = {}, q2 = {};
            q0 = __builtin_amdgcn_mfma_f32_16x16x32_f16(ah[mt], bh, q0, 0, 0, 0);
            q1 = __builtin_amdgcn_mfma_f32_16x16x32_f16(ah[mt], bl, q1, 0, 0, 0);
            q1 = __builtin_amdgcn_mfma_f32_16x16x32_f16(al[mt], bh, q1, 0, 0, 0);
            q2 = __builtin_amdgcn_mfma_f32_16x16x32_f16(al[mt], bl, q2, 0, 0, 0);
            #pragma unroll
            for (int r = 0; r < 4; ++r) {
                const int m = mt * 16 + quad * 4 + r;
                float v = q0[r] + c1 * q1[r] + c2 * q2[r] + bv;
                v = fmaxf(v, 0.f);
                _Float16 t = (_Float16)v;
                h2h[m * HSTR + col] = t;
                h2l[m * HSTR + col] = (_Float16)((v - (float)t) * 2048.0f);
            }
        }
    }
    __syncthreads();

    // ---------------- phase 4: recon = h2 @ W4 + b4 (4-slot pairing) --------
    {
        _Float16* sBhi = R0h;                   // [4][128*40]
        _Float16* sBlo = R0h + 4 * 128 * 40;    // byte 40960; total 81920 ✓
        _Float16* h2h  = hP;
        _Float16* h2l  = hP + 32 * HSTR;
        const int mt  = wv >> 3;                // 0..1 (row half)
        const int ntw = wv & 7;                 // 0..7 (col group)
        const int brow = tid >> 2;              // staging: tid<512 -> 0..127
        const int bk4  = (tid & 3) * 8;
        h8 rbh[2], rbl[2];                      // reg slots by step parity
        auto pf = [&](int ss) {
            if (tid < 512 && ss < 56) {
                int rg = (ss >> 3) * 128 + brow;
                if (rg > ND - 1) rg = ND - 1;
                const int k = (ss & 7) * 32 + bk4;
                rbh[ss & 1] = *(const h8*)(w4thi + (size_t)rg * NH + k);
                rbl[ss & 1] = *(const h8*)(w4tlo + (size_t)rg * NH + k);
            }
        };
        auto cm = [&](int ss) {
            if (tid < 512 && ss < 56) {
                const int sl = ss & 3;
                *(h8*)&sBhi[sl * 128 * 40 + brow * 40 + bk4] = rbh[ss & 1];
                *(h8*)&sBlo[sl * 128 * 40 + brow * 40 + bk4] = rbl[ss & 1];
            }
        };
        pf(0); pf(1); cm(0); cm(1); pf(2); pf(3);
        __syncthreads();

        f32x4 q0 = {}, q1 = {};
        auto step = [&](int t) {
            const int sl = t & 3, ks = t & 7;
            const int bo = sl * 128 * 40 + (ntw * 16 + li) * 40 + kq;
            h8 fbh = *(const h8*)&sBhi[bo];
            h8 fbl = *(const h8*)&sBlo[bo];
            const int k = ks * 32 + kq;
            h8 ah = *(const h8*)&h2h[(mt * 16 + li) * HSTR + k];
            h8 al = *(const h8*)&h2l[(mt * 16 + li) * HSTR + k];
            q0 = __builtin_amdgcn_mfma_f32_16x16x32_f16(ah, fbh, q0, 0, 0, 0);
            q1 = __builtin_amdgcn_mfma_f32_16x16x32_f16(ah, fbl, q1, 0, 0, 0);
            q1 = __builtin_amdgcn_mfma_f32_16x16x32_f16(al, fbh, q1, 0, 0, 0);
            if (ks == 7) {
                const int n = (t >> 3) * 128 + ntw * 16 + li;
                if (n < ND) {
                    const float bv = b4[n];
                    #pragma unroll
                    for (int r = 0; r < 4; ++r) {
                        const int m = mt * 16 + quad * 4 + r;
                        recon_g[(size_t)(r0 + m) * ND + n] = q0[r] + c1 * q1[r] + bv;
                    }
                }
                q0 = {}; q1 = {};
            }
        };
        for (int ii = 0; ii < 28; ++ii) {
            const int s0 = ii * 2;
            step(s0);
            step(s0 + 1);
            cm(s0 + 2); cm(s0 + 3);     // write slots (s0+2)&3,(s0+3)&3 — the
            pf(s0 + 4); pf(s0 + 5);     // pair NOT being read this interval
            __syncthreads();
        }
    }
    __syncthreads();

    // ---------------- phase 5: distances + stable softmin -------------------
    {
        float* tr0 = (float*)lds;               // [16][520] rows 0-15
        float* tr1 = (float*)(lds + 33280);     // [16][520] rows 16-31
        const int half = tid >> 9;              // 0: rows 0-15, 1: rows 16-31
        const int cl   = tid & 511;             // cluster id
        float* trh = half ? tr1 : tr0;
        const int rbase = half * 16;

        const float* rp = reps + (size_t)cl * NE;
        f32x4 rv[8];
        #pragma unroll
        for (int e4 = 0; e4 < 8; ++e4) rv[e4] = ((const f32x4*)rp)[e4];

        float d[16];
        #pragma unroll
        for (int r = 0; r < 16; ++r) {
            float a = 0.f;
            #pragma unroll
            for (int e4 = 0; e4 < 8; ++e4) {
                f32x4 ev = *(const f32x4*)&es[(rbase + r) * 36 + e4 * 4];  // broadcast
                #pragma unroll
                for (int j = 0; j < 4; ++j) {
                    float t = ev[j] - rv[e4][j];
                    a = fmaf(t, t, a);
                }
            }
            d[r] = a;
            trh[r * 520 + cl] = a;
        }
        __syncthreads();
        {   // min-reduce: wave handles 2 rows of its half; stride-64 scalar
            const int w8 = wv & 7;
            #pragma unroll
            for (int p = 0; p < 2; ++p) {
                const int rl = w8 * 2 + p;
                float m = trh[rl * 520 + lane];
                #pragma unroll
                for (int j = 1; j < 8; ++j)
                    m = fminf(m, trh[rl * 520 + lane + 64 * j]);
                #pragma unroll
                for (int off = 32; off > 0; off >>= 1)
                    m = fminf(m, __shfl_xor(m, off, 64));
                if (lane == 0) rmin[rbase + rl] = m;
            }
        }
        __syncthreads();
        #pragma unroll
        for (int r = 0; r < 16; ++r)
            trh[r * 520 + cl] = expf(-ALPHA_F * (d[r] - rmin[rbase + r]));
        __syncthreads();
        {   // sum-reduce
            const int w8 = wv & 7;
            #pragma unroll
            for (int p = 0; p < 2; ++p) {
                const int rl = w8 * 2 + p;
                float s = trh[rl * 520 + lane];
                #pragma unroll
                for (int j = 1; j < 8; ++j)
                    s += trh[rl * 520 + lane + 64 * j];
                #pragma unroll
                for (int off = 32; off > 0; off >>= 1)
                    s += __shfl_xor(s, off, 64);
                if (lane == 0) rinv[rbase + rl] = 1.0f / s;
            }
        }
        __syncthreads();
        #pragma unroll
        for (int r = 0; r < 16; ++r) {
            const size_t row = (size_t)(r0 + rbase + r);
            const float ev = trh[r * 520 + cl];      // exps still live in LDS
            dist_g[row * NK + cl] = d[r];
            wout_g[row * NK + cl] = d[r] * (ev * rinv[rbase + r]);
        }
    }
}

// ===========================================================================
// Fallback path (no/insufficient workspace): original verified 5-launch chain.
// ===========================================================================
__global__ __launch_bounds__(256)
void splitw2_kernel(const float* __restrict__ W1, _Float16* __restrict__ w1thi,
                    _Float16* __restrict__ w1tlo,
                    const float* __restrict__ W4, _Float16* __restrict__ w4thi,
                    _Float16* __restrict__ w4tlo) {
    const int b = blockIdx.x;
    const float* W; _Float16 *hi, *lo; int K, N, n;
    if (b < NH) { W = W1; hi = w1thi; lo = w1tlo; K = ND; N = NH; n = b; }
    else        { W = W4; hi = w4thi; lo = w4tlo; K = NH; N = ND; n = b - NH; }
    for (int k = threadIdx.x; k < K; k += 256) {
        float w = W[(size_t)k * N + n];
        _Float16 hh = (_Float16)w;
        float r = w - (float)hh;
        hi[(size_t)n * K + k] = hh;
        lo[(size_t)n * K + k] = (_Float16)(r * 2048.0f);
    }
}

template<int TERMS, bool RELU, bool SPLITA, int MT>
__global__ __launch_bounds__(256)
void mfma_gemm3(const float* __restrict__ Af32,
                const _Float16* __restrict__ Ahi_g,
                const _Float16* __restrict__ Alo_g,
                const _Float16* __restrict__ WThi,
                const _Float16* __restrict__ WTlo,
                const float* __restrict__ bias, float* __restrict__ C,
                int N, int K, int KS) {
    constexpr int BM  = MT * 32;
    constexpr int ACH = BM / 64;
    constexpr int AS  = BM * 40;
    constexpr int BS  = 64 * 40;
    __shared__ __align__(16) _Float16 smem[2 * BM * 40 * 2 + 2 * 64 * 40 * 2];
    _Float16* sAhi = smem;
    _Float16* sAlo = sAhi + 2 * BM * 40;
    _Float16* sBhi = sAlo + 2 * BM * 40;
    _Float16* sBlo = sBhi + 2 * 64 * 40;

    const int tid = threadIdx.x;
    const int bm  = blockIdx.x * BM;
    const int bn  = blockIdx.y * 64;

    const int arow = (ACH == 1) ? (tid >> 2) : (tid >> 1);
    const int ak   = (ACH == 1) ? ((tid & 3) * 8) : ((tid & 1) * 16);
    const int brow = tid >> 2;
    const int bk   = (tid & 3) * 8;

    const float*    pA32 = SPLITA ? Af32 + (size_t)(bm + arow) * K : nullptr;
    const _Float16* pAhi = SPLITA ? nullptr : Ahi_g + (size_t)(bm + arow) * K;
    const _Float16* pAlo = SPLITA ? nullptr : Alo_g + (size_t)(bm + arow) * K;
    int brow_g = bn + brow; if (brow_g > N - 1) brow_g = N - 1;
    const _Float16* pBhi = WThi + (size_t)brow_g * K;
    const _Float16* pBlo = WTlo + (size_t)brow_g * K;

    float araw[ACH * 8];
    h8 rahi[ACH], ralo[ACH];
    h8 rbhi, rblo;

    auto prefetch = [&](int s) {
        #pragma unroll
        for (int c = 0; c < ACH; ++c) {
            const int k = s * 32 + ak + c * 8;
            if (SPLITA) {
                if (k + 8 <= K) {
                    f32x4 v0 = *(const f32x4*)(pA32 + k);
                    f32x4 v1 = *(const f32x4*)(pA32 + k + 4);
                    #pragma unroll
                    for (int j = 0; j < 4; ++j) {
                        araw[c * 8 + j]     = v0[j];
                        araw[c * 8 + 4 + j] = v1[j];
                    }
                } else {
                    #pragma unroll
                    for (int j = 0; j < 8; ++j) araw[c * 8 + j] = 0.f;
                }
            } else {
                rahi[c] = (k + 8 <= K) ? *(const h8*)(pAhi + k) : (h8){};
                ralo[c] = (k + 8 <= K) ? *(const h8*)(pAlo + k) : (h8){};
            }
        }
        const int kb = s * 32 + bk;
        rbhi = (kb + 8 <= K) ? *(const h8*)(pBhi + kb) : (h8){};
        rblo = (kb + 8 <= K) ? *(const h8*)(pBlo + kb) : (h8){};
    };

    auto commit = [&](int buf) {
        #pragma unroll
        for (int c = 0; c < ACH; ++c) {
            h8 hi, lo;
            if (SPLITA) {
                #pragma unroll
                for (int j = 0; j < 8; ++j) {
                    float v = araw[c * 8 + j];
                    _Float16 hh = (_Float16)v;
                    hi[j] = hh;
                    lo[j] = (_Float16)((v - (float)hh) * 2048.0f);
                }
            } else { hi = rahi[c]; lo = ralo[c]; }
            *(h8*)&sAhi[buf * AS + arow * 40 + ak + c * 8] = hi;
            *(h8*)&sAlo[buf * AS + arow * 40 + ak + c * 8] = lo;
        }
        *(h8*)&sBhi[buf * BS + brow * 40 + bk] = rbhi;
        *(h8*)&sBlo[buf * BS + brow * 40 + bk] = rblo;
    };

    prefetch(0);
    commit(0);
    prefetch(1);
    __syncthreads();

    const int lane = tid & 63;
    const int wv   = tid >> 6;
    const int wm   = (wv >> 1) * (MT * 16);
    const int wn   = (wv & 1) * 32;
    const int li   = lane & 15;
    const int kq   = (lane >> 4) * 8;

    f32x4 acc0[MT][2] = {};
    f32x4 acc1[MT][2] = {};
    f32x4 acc2[MT][2] = {};

    for (int s = 0; s < KS; ++s) {
        const int buf = s & 1;
        h8 fahi[MT], falo[MT], fbhi[2], fblo[2];
        #pragma unroll
        for (int mt = 0; mt < MT; ++mt) {
            const int ao = buf * AS + (wm + mt * 16 + li) * 40 + kq;
            fahi[mt] = *(const h8*)&sAhi[ao];
            falo[mt] = *(const h8*)&sAlo[ao];
        }
        #pragma unroll
        for (int nt = 0; nt < 2; ++nt) {
            const int bo = buf * BS + (wn + nt * 16 + li) * 40 + kq;
            fbhi[nt] = *(const h8*)&sBhi[bo];
            fblo[nt] = *(const h8*)&sBlo[bo];
        }
        #pragma unroll
        for (int mt = 0; mt < MT; ++mt)
            #pragma unroll
            for (int nt = 0; nt < 2; ++nt) {
                acc0[mt][nt] = __builtin_amdgcn_mfma_f32_16x16x32_f16(
                    fahi[mt], fbhi[nt], acc0[mt][nt], 0, 0, 0);
                acc1[mt][nt] = __builtin_amdgcn_mfma_f32_16x16x32_f16(
                    fahi[mt], fblo[nt], acc1[mt][nt], 0, 0, 0);
                acc1[mt][nt] = __builtin_amdgcn_mfma_f32_16x16x32_f16(
                    falo[mt], fbhi[nt], acc1[mt][nt], 0, 0, 0);
                if (TERMS == 4)
                    acc2[mt][nt] = __builtin_amdgcn_mfma_f32_16x16x32_f16(
                        falo[mt], fblo[nt], acc2[mt][nt], 0, 0, 0);
            }
        if (s + 1 < KS) {
            commit((s + 1) & 1);
            if (s + 2 < KS) prefetch(s + 2);
        }
        __syncthreads();
    }

    const float c1 = 1.0f / 2048.0f;
    const float c2 = c1 * c1;
    const int quad = lane >> 4;
    #pragma unroll
    for (int nt = 0; nt < 2; ++nt) {
        const int n = bn + wn + nt * 16 + li;
        if (n < N) {
            const float bv = bias[n];
            #pragma unroll
            for (int mt = 0; mt < MT; ++mt) {
                #pragma unroll
                for (int r = 0; r < 4; ++r) {
                    const int m = bm + wm + mt * 16 + quad * 4 + r;
                    float v = acc0[mt][nt][r] + c1 * acc1[mt][nt][r];
                    if (TERMS == 4) v += c2 * acc2[mt][nt][r];
                    v += bv;
                    if (RELU) v = fmaxf(v, 0.f);
                    C[(size_t)m * N + n] = v;
                }
            }
        }
    }
}

__global__ __launch_bounds__(256)
void mid_kernel(const float* __restrict__ h, const float* __restrict__ W2,
                const float* __restrict__ b2, const float* __restrict__ W3,
                const float* __restrict__ b3, float* __restrict__ emb,
                _Float16* __restrict__ h2hi, _Float16* __restrict__ h2lo) {
    __shared__ float es[16][32];
    const int tid = threadIdx.x;
    const int r0  = blockIdx.x * 16;

    #pragma unroll
    for (int half = 0; half < 2; ++half) {
        const int o   = tid + half * 256;
        const int row = o >> 5;
        const int col = o & 31;
        const float* hrow = h + (size_t)(r0 + row) * NH;
        float acc0 = 0.f, acc1 = 0.f;
        #pragma unroll 4
        for (int k = 0; k < NH; k += 4) {
            float4 hv = *(const float4*)(hrow + k);
            acc0 = fmaf(hv.x, W2[(k + 0) * NE + col], acc0);
            acc1 = fmaf(hv.y, W2[(k + 1) * NE + col], acc1);
            acc0 = fmaf(hv.z, W2[(k + 2) * NE + col], acc0);
            acc1 = fmaf(hv.w, W2[(k + 3) * NE + col], acc1);
        }
        float v = acc0 + acc1 + b2[col];
        es[row][col] = v;
        emb[(size_t)r0 * NE + o] = v;
    }
    __syncthreads();

    const int col = tid;
    float acc[16];
    #pragma unroll
    for (int r = 0; r < 16; ++r) acc[r] = 0.f;
    #pragma unroll
    for (int k = 0; k < NE; ++k) {
        float w = W3[k * NH + col];
        #pragma unroll
        for (int r = 0; r < 16; ++r) acc[r] = fmaf(es[r][k], w, acc[r]);
    }
    const float bb = b3[col];
    #pragma unroll
    for (int r = 0; r < 16; ++r) {
        float v = acc[r] + bb;
        v = v > 0.f ? v : 0.f;
        _Float16 hh = (_Float16)v;
        float rr = v - (float)hh;
        h2hi[(size_t)(r0 + r) * NH + col] = hh;
        h2lo[(size_t)(r0 + r) * NH + col] = (_Float16)(rr * 2048.0f);
    }
}

__global__ __launch_bounds__(512, 4)
void dist_kernel(const float* __restrict__ emb, const float* __restrict__ reps,
                 float* __restrict__ dist, float* __restrict__ wout) {
    __shared__ float es[8][32];
    __shared__ float tr[8][520];
    __shared__ float rmin[8];
    __shared__ float rinv[8];

    const int tid = threadIdx.x;
    const int r0  = blockIdx.x * 8;

    if (tid < 256) es[tid >> 5][tid & 31] = emb[(size_t)r0 * NE + tid];

    const float* rp = reps + (size_t)tid * NE;
    f32x4 rv[8];
    #pragma unroll
    for (int e4 = 0; e4 < 8; ++e4) rv[e4] = ((const f32x4*)rp)[e4];
    __syncthreads();

    float d[8];
    #pragma unroll
    for (int r = 0; r < 8; ++r) {
        float a = 0.f;
        #pragma unroll
        for (int e4 = 0; e4 < 8; ++e4) {
            f32x4 ev = *(const f32x4*)&es[r][e4 * 4];
            #pragma unroll
            for (int j = 0; j < 4; ++j) {
                float t = ev[j] - rv[e4][j];
                a = fmaf(t, t, a);
            }
        }
        d[r] = a;
    }

    const int lane = tid & 63;
    const int wv   = tid >> 6;

    #pragma unroll
    for (int r = 0; r < 8; ++r) tr[r][tid] = d[r];
    __syncthreads();
    {
        f32x4 a = *(const f32x4*)&tr[wv][lane * 8];
        f32x4 b = *(const f32x4*)&tr[wv][lane * 8 + 4];
        float m = fminf(fminf(fminf(a[0], a[1]), fminf(a[2], a[3])),
                        fminf(fminf(b[0], b[1]), fminf(b[2], b[3])));
        #pragma unroll
        for (int off = 32; off > 0; off >>= 1)
            m = fminf(m, __shfl_xor(m, off, 64));
        if (lane == 0) rmin[wv] = m;
    }
    __syncthreads();

    float e[8];
    #pragma unroll
    for (int r = 0; r < 8; ++r) {
        e[r] = expf(-ALPHA_F * (d[r] - rmin[r]));
        tr[r][tid] = e[r];
    }
    __syncthreads();
    {
        f32x4 a = *(const f32x4*)&tr[wv][lane * 8];
        f32x4 b = *(const f32x4*)&tr[wv][lane * 8 + 4];
        float s = ((a[0] + a[1]) + (a[2] + a[3])) +
                  ((b[0] + b[1]) + (b[2] + b[3]));
        #pragma unroll
        for (int off = 32; off > 0; off >>= 1)
            s += __shfl_xor(s, off, 64);
        if (lane == 0) rinv[wv] = 1.0f / s;
    }
    __syncthreads();

    #pragma unroll
    for (int r = 0; r < 8; ++r) {
        const size_t row = (size_t)(r0 + r);
        dist[row * NK + tid] = d[r];
        wout[row * NK + tid] = d[r] * (e[r] * rinv[r]);
    }
}

// ---------------------------------------------------------------------------
extern "C" void kernel_launch(void* const* d_in, const int* in_sizes, int n_in,
                              void* d_out, int out_size, void* d_ws, size_t ws_size,
                              hipStream_t stream) {
    const float* x    = (const float*)d_in[0];
    const float* reps = (const float*)d_in[1];
    const float* W1   = (const float*)d_in[2];
    const float* b1   = (const float*)d_in[3];
    const float* W2   = (const float*)d_in[4];
    const float* b2   = (const float*)d_in[5];
    const float* W3   = (const float*)d_in[6];
    const float* b3   = (const float*)d_in[7];
    const float* W4   = (const float*)d_in[8];
    const float* b4   = (const float*)d_in[9];

    float* out   = (float*)d_out;
    float* wout  = out;                                          // [8192,512]
    float* dist  = out + (size_t)NB * NK;                        // [8192,512]
    float* recon = out + (size_t)2 * NB * NK;                    // [8192,784]
    float* emb   = out + (size_t)2 * NB * NK + (size_t)NB * ND;  // [8192,32]

    // Workspace: weight planes only (~1.7 MB): W1T, W4T, W2T, W3T hi/lo.
    const size_t nW14 = (size_t)ND * NH;     // 200704 halves per plane
    const size_t nW23 = (size_t)NE * NH;     // 8192 halves per plane
    const size_t wneed = (4 * nW14 + 4 * nW23) * sizeof(_Float16);

    if (d_ws != nullptr && ws_size >= wneed) {
        _Float16* w1thi = (_Float16*)d_ws;
        _Float16* w1tlo = w1thi + nW14;
        _Float16* w4thi = w1tlo + nW14;
        _Float16* w4tlo = w4thi + nW14;
        _Float16* w2thi = w4tlo + nW14;
        _Float16* w2tlo = w2thi + nW23;
        _Float16* w3thi = w2tlo + nW23;
        _Float16* w3tlo = w3thi + nW23;

        prep4_kernel<<<NBW1 + NBW4 + NBW2 + NBW3, 256, 0, stream>>>(
            W1, w1thi, w1tlo, W4, w4thi, w4tlo,
            W2, w2thi, w2tlo, W3, w3thi, w3tlo);

        mega_kernel<<<NB / 32, 1024, 0, stream>>>(
            x, reps, w1thi, w1tlo, w2thi, w2tlo, w3thi, w3tlo, w4thi, w4tlo,
            b1, b2, b3, b4, emb, recon, dist, wout);
    } else {
        // Fallback: original serialized 5-launch path with output-aliased
        // scratch (safe because launches are ordered).
        float* h = dist;
        _Float16* h2hi  = (_Float16*)(dist + (size_t)NB * NH);
        _Float16* h2lo  = h2hi + (size_t)NB * NH;
        _Float16* w1thi = (_Float16*)wout;
        _Float16* w1tlo = w1thi + (size_t)NH * ND;
        _Float16* w4thi = w1tlo + (size_t)NH * ND;
        _Float16* w4tlo = w4thi + (size_t)ND * NH;

        splitw2_kernel<<<NH + ND, 256, 0, stream>>>(W1, w1thi, w1tlo,
                                                    W4, w4thi, w4tlo);
        mfma_gemm3<4, true, true, 2><<<dim3(128, 4), 256, 0, stream>>>(
            x, nullptr, nullptr, w1thi, w1tlo, b1, h, NH, ND, 25);
        mid_kernel<<<NB / 16, 256, 0, stream>>>(h, W2, b2, W3, b3,
                                                emb, h2hi, h2lo);
        mfma_gemm3<3, false, false, 4><<<dim3(64, 13), 256, 0, stream>>>(
            nullptr, h2hi, h2lo, w4thi, w4tlo, b4, recon, ND, NH, 8);
        dist_kernel<<<NB / 8, 512, 0, stream>>>(emb, reps, dist, wout);
    }
}

// Round 9
// 158.448 us; speedup vs baseline: 1.0259x; 1.0259x over previous
//
#include <hip/hip_runtime.h>
#include <cstddef>

// Sizes (fixed per reference): B=8192, D=784, H=256, E=32, K=512
#define NB 8192
#define ND 784
#define NH 256
#define NE 32
#define NK 512
#define ALPHA_F 1000.0f

typedef _Float16 h8 __attribute__((ext_vector_type(8)));
typedef float f32x4 __attribute__((ext_vector_type(4)));

// ---------------------------------------------------------------------------
// prep4: W [K][N] fp32 -> WT hi/lo fp16 planes [N][K], via 32x32 LDS tiles.
// ---------------------------------------------------------------------------
#define TW1 25
#define TN1 8
#define NBW1 200        // W1 784x256
#define TW4 8
#define TN4 25
#define NBW4 200        // W4 256x784
#define NBW2 8          // W2 256x32
#define NBW3 8          // W3 32x256

__global__ __launch_bounds__(256)
void prep4_kernel(const float* __restrict__ W1, _Float16* __restrict__ w1thi,
                  _Float16* __restrict__ w1tlo,
                  const float* __restrict__ W4, _Float16* __restrict__ w4thi,
                  _Float16* __restrict__ w4tlo,
                  const float* __restrict__ W2, _Float16* __restrict__ w2thi,
                  _Float16* __restrict__ w2tlo,
                  const float* __restrict__ W3, _Float16* __restrict__ w3thi,
                  _Float16* __restrict__ w3tlo) {
    __shared__ float tile[32][33];
    const int b   = blockIdx.x;
    const int tid = threadIdx.x;

    const float* W; _Float16 *hi, *lo; int K, N, kt, nt;
    if (b < NBW1) {
        W = W1; hi = w1thi; lo = w1tlo; K = ND; N = NH;
        kt = b % TW1; nt = b / TW1;
    } else if (b < NBW1 + NBW4) {
        const int bb = b - NBW1;
        W = W4; hi = w4thi; lo = w4tlo; K = NH; N = ND;
        kt = bb % TW4; nt = bb / TW4;
    } else if (b < NBW1 + NBW4 + NBW2) {
        W = W2; hi = w2thi; lo = w2tlo; K = NH; N = NE;
        kt = b - (NBW1 + NBW4); nt = 0;
    } else {
        W = W3; hi = w3thi; lo = w3tlo; K = NE; N = NH;
        kt = 0; nt = b - (NBW1 + NBW4 + NBW2);
    }
    const int k0 = kt * 32, n0 = nt * 32;
    const int row = tid >> 3, c4 = (tid & 7) * 4;
    #pragma unroll
    for (int j = 0; j < 4; ++j) {
        const int k = k0 + row, n = n0 + c4 + j;
        tile[row][c4 + j] = (k < K && n < N) ? W[(size_t)k * N + n] : 0.f;
    }
    __syncthreads();
    const int n = n0 + row;
    if (n < N) {
        #pragma unroll
        for (int j = 0; j < 4; ++j) {
            const int k = k0 + c4 + j;
            if (k < K) {
                float w = tile[c4 + j][row];
                _Float16 hh = (_Float16)w;
                float r = w - (float)hh;
                hi[(size_t)n * K + k] = hh;
                lo[(size_t)n * K + k] = (_Float16)(r * 2048.0f);
            }
        }
    }
}

// ---------------------------------------------------------------------------
// MEGA v5 = v4 schedule with CONFLICT-FREE LDS LAYOUTS: every staged tile is
// K-step-blocked, unpadded [ks][row][32 halves], so each wave fragment read
// is a contiguous 1024B window (lane i -> base + i*16B, canonical pattern)
// and every commit is base + 16*tid. Same math/barriers as v4.
// 1024 threads (16 waves), LDS 116480B -> 1 block/CU.
// ---------------------------------------------------------------------------
__global__ __launch_bounds__(1024, 4)
void mega_kernel(const float* __restrict__ x, const float* __restrict__ reps,
                 const _Float16* __restrict__ w1thi, const _Float16* __restrict__ w1tlo,
                 const _Float16* __restrict__ w2thi, const _Float16* __restrict__ w2tlo,
                 const _Float16* __restrict__ w3thi, const _Float16* __restrict__ w3tlo,
                 const _Float16* __restrict__ w4thi, const _Float16* __restrict__ w4tlo,
                 const float* __restrict__ b1, const float* __restrict__ b2,
                 const float* __restrict__ b3, const float* __restrict__ b4,
                 float* __restrict__ emb_g, float* __restrict__ recon_g,
                 float* __restrict__ dist_g, float* __restrict__ wout_g) {
    // LDS map (bytes):
    // [0,66560)       R0: ph1 sB dbuf [2][8192]h x2 (65536) | ph2 W2 [8][32][32]h x2
    //                 | ph3 W3 [256][32]h x2 | ph4 sB [4][4096]h x2 (65536)
    //                 | ph5 tr0 [16][520]f @0 + tr1 @33280
    // [66560,74752)   sA dbuf [2][1024]h x2
    // [74752,107520)  h / h2 planes [8][32][32]h x2
    // [107520,112128) es f32 [32][36]
    // [112128,116224) emb planes [32][32]h x2
    // [116224,116480) rmin[32], rinv[32]
    __shared__ __align__(16) unsigned char lds[116480];
    _Float16* R0h  = (_Float16*)lds;
    _Float16* sA   = (_Float16*)(lds + 66560);
    _Float16* hP   = (_Float16*)(lds + 74752);
    float*    es   = (float*)(lds + 107520);
    _Float16* eP   = (_Float16*)(lds + 112128);
    float*    rmin = (float*)(lds + 116224);
    float*    rinv = (float*)(lds + 116352);

    const int tid  = threadIdx.x;
    const int lane = tid & 63;
    const int wv   = tid >> 6;          // 0..15
    const int li   = lane & 15;
    const int kq   = (lane >> 4) * 8;
    const int quad = lane >> 4;
    const int r0   = blockIdx.x * 32;

    const float c1 = 1.0f / 2048.0f;
    const float c2 = c1 * c1;

    // ---------------- phase 1: h planes = split(relu(x @ W1 + b1)) ----------
    {
        _Float16* sBhi = R0h;                   // [2][8192]
        _Float16* sBlo = R0h + 2 * 8192;
        _Float16* sAhi = sA;                    // [2][1024]
        _Float16* sAlo = sA + 2 * 1024;
        const int aro  = tid >> 2;              // A: tid<128 -> rows 0..31
        const int ak   = (tid & 3) * 8;
        const int brow = tid >> 2;              // B: 0..255
        const int bk   = (tid & 3) * 8;
        const float*    pA  = x + (size_t)(r0 + aro) * ND;
        const _Float16* pBh = w1thi + (size_t)brow * ND;
        const _Float16* pBl = w1tlo + (size_t)brow * ND;

        float araw[8];
        h8 rbh, rbl;

        auto pf = [&](int s) {
            if (tid < 128) {
                const int k = s * 32 + ak;
                if (k + 8 <= ND) {
                    f32x4 v0 = *(const f32x4*)(pA + k);
                    f32x4 v1 = *(const f32x4*)(pA + k + 4);
                    #pragma unroll
                    for (int j = 0; j < 4; ++j) {
                        araw[j] = v0[j]; araw[4 + j] = v1[j];
                    }
                } else {
                    #pragma unroll
                    for (int j = 0; j < 8; ++j) araw[j] = 0.f;
                }
            }
            const int kb = s * 32 + bk;
            rbh = (kb + 8 <= ND) ? *(const h8*)(pBh + kb) : (h8){};
            rbl = (kb + 8 <= ND) ? *(const h8*)(pBl + kb) : (h8){};
        };
        auto cm = [&](int buf) {
            if (tid < 128) {
                h8 hi, lo;
                #pragma unroll
                for (int j = 0; j < 8; ++j) {
                    float v = araw[j];
                    _Float16 hh = (_Float16)v;
                    hi[j] = hh;
                    lo[j] = (_Float16)((v - (float)hh) * 2048.0f);
                }
                *(h8*)&sAhi[buf * 1024 + aro * 32 + ak] = hi;   // 16*tid contig
                *(h8*)&sAlo[buf * 1024 + aro * 32 + ak] = lo;
            }
            *(h8*)&sBhi[buf * 8192 + brow * 32 + bk] = rbh;     // 16*tid contig
            *(h8*)&sBlo[buf * 8192 + brow * 32 + bk] = rbl;
        };

        pf(0); cm(0); pf(1);
        __syncthreads();

        f32x4 a0[2] = {}, a1[2] = {}, a2[2] = {};
        for (int s = 0; s < 25; ++s) {
            const int buf = s & 1;
            h8 fah[2], fal[2];
            #pragma unroll
            for (int mt = 0; mt < 2; ++mt) {
                const int ao = buf * 1024 + (mt * 16 + li) * 32 + kq;  // contig 1KB
                fah[mt] = *(const h8*)&sAhi[ao];
                fal[mt] = *(const h8*)&sAlo[ao];
            }
            const int bo = buf * 8192 + (wv * 16 + li) * 32 + kq;      // contig 1KB
            h8 fbh = *(const h8*)&sBhi[bo];
            h8 fbl = *(const h8*)&sBlo[bo];
            #pragma unroll
            for (int mt = 0; mt < 2; ++mt) {
                a0[mt] = __builtin_amdgcn_mfma_f32_16x16x32_f16(fah[mt], fbh, a0[mt], 0, 0, 0);
                a1[mt] = __builtin_amdgcn_mfma_f32_16x16x32_f16(fah[mt], fbl, a1[mt], 0, 0, 0);
                a1[mt] = __builtin_amdgcn_mfma_f32_16x16x32_f16(fal[mt], fbh, a1[mt], 0, 0, 0);
                a2[mt] = __builtin_amdgcn_mfma_f32_16x16x32_f16(fal[mt], fbl, a2[mt], 0, 0, 0);
            }
            if (s + 1 < 25) { cm((s + 1) & 1); if (s + 2 < 25) pf(s + 2); }
            __syncthreads();
        }
        // epilogue -> h planes [8][32][32]
        _Float16* hhi = hP;
        _Float16* hlo = hP + 8192;
        const int n  = wv * 16 + li;
        const int nb = n >> 5, nr = n & 31;
        const float bv = b1[n];
        #pragma unroll
        for (int mt = 0; mt < 2; ++mt)
            #pragma unroll
            for (int r = 0; r < 4; ++r) {
                const int m = mt * 16 + quad * 4 + r;
                float v = a0[mt][r] + c1 * a1[mt][r] + c2 * a2[mt][r] + bv;
                v = fmaxf(v, 0.f);
                _Float16 t = (_Float16)v;
                hhi[nb * 1024 + m * 32 + nr] = t;
                hlo[nb * 1024 + m * 32 + nr] = (_Float16)((v - (float)t) * 2048.0f);
            }
    }
    __syncthreads();

    // ---------------- phase 2: emb = h @ W2 + b2 ----------------------------
    {   // stage W2T planes [32 col][256 k] -> LDS [8 ks][32 col][32]
        _Float16* w2h = R0h;                    // [8192]
        _Float16* w2l = R0h + 8192;
        const int col = tid >> 5;               // 0..31
        const int k8  = tid & 31;               // h8 chunk 0..31
        const int src = col * 256 + k8 * 8;
        const int dst = (k8 >> 2) * 1024 + col * 32 + (k8 & 3) * 8;
        *(h8*)&w2h[dst] = *(const h8*)(w2thi + src);
        *(h8*)&w2l[dst] = *(const h8*)(w2tlo + src);
    }
    __syncthreads();
    if (wv < 4) {
        const int mt = wv >> 1, nt = wv & 1;
        _Float16* hhi = hP;
        _Float16* hlo = hP + 8192;
        _Float16* w2h = R0h;
        _Float16* w2l = R0h + 8192;
        f32x4 e0 = {}, e1 = {}, e2 = {};
        #pragma unroll
        for (int ks = 0; ks < 8; ++ks) {
            h8 ah = *(const h8*)&hhi[ks * 1024 + (mt * 16 + li) * 32 + kq];
            h8 al = *(const h8*)&hlo[ks * 1024 + (mt * 16 + li) * 32 + kq];
            h8 bh = *(const h8*)&w2h[ks * 1024 + (nt * 16 + li) * 32 + kq];
            h8 bl = *(const h8*)&w2l[ks * 1024 + (nt * 16 + li) * 32 + kq];
            e0 = __builtin_amdgcn_mfma_f32_16x16x32_f16(ah, bh, e0, 0, 0, 0);
            e1 = __builtin_amdgcn_mfma_f32_16x16x32_f16(ah, bl, e1, 0, 0, 0);
            e1 = __builtin_amdgcn_mfma_f32_16x16x32_f16(al, bh, e1, 0, 0, 0);
            e2 = __builtin_amdgcn_mfma_f32_16x16x32_f16(al, bl, e2, 0, 0, 0);
        }
        const int col = nt * 16 + li;
        const float bv = b2[col];
        _Float16* eh = eP;                      // [32][32]
        _Float16* el = eP + 1024;
        #pragma unroll
        for (int r = 0; r < 4; ++r) {
            const int m = mt * 16 + quad * 4 + r;
            float v = e0[r] + c1 * e1[r] + c2 * e2[r] + bv;
            es[m * 36 + col] = v;
            _Float16 t = (_Float16)v;
            eh[m * 32 + col] = t;
            el[m * 32 + col] = (_Float16)((v - (float)t) * 2048.0f);
            emb_g[(size_t)(r0 + m) * NE + col] = v;
        }
    }
    __syncthreads();

    // ---------------- phase 3: h2 planes = split(relu(emb @ W3 + b3)) -------
    {   // stage W3T planes [256][32] -> LDS [256][32] (direct contiguous copy)
        _Float16* w3h = R0h;
        _Float16* w3l = R0h + 8192;
        const int o = tid * 8;
        *(h8*)&w3h[o] = *(const h8*)(w3thi + o);
        *(h8*)&w3l[o] = *(const h8*)(w3tlo + o);
    }
    __syncthreads();
    {
        _Float16* w3h  = R0h;
        _Float16* w3l  = R0h + 8192;
        _Float16* h2h  = hP;                    // overlays h (dead after ph2)
        _Float16* h2l  = hP + 8192;
        _Float16* eh   = eP;
        _Float16* el   = eP + 1024;
        h8 ah[2], al[2];
        #pragma unroll
        for (int mt = 0; mt < 2; ++mt) {
            ah[mt] = *(const h8*)&eh[(mt * 16 + li) * 32 + kq];
            al[mt] = *(const h8*)&el[(mt * 16 + li) * 32 + kq];
        }
        const int col = wv * 16 + li;
        h8 bh = *(const h8*)&w3h[col * 32 + kq];
        h8 bl = *(const h8*)&w3l[col * 32 + kq];
        const float bv = b3[col];
        const int cb = col >> 5, cr = col & 31;
        #pragma unroll
        for (int mt = 0; mt < 2; ++mt) {
            f32x4 q0 = {}, q1 = {}, q2 = {};
            q0 = __builtin_amdgcn_mfma_f32_16x16x32_f16(ah[mt], bh, q0, 0, 0, 0);
            q1 = __builtin_amdgcn_mfma_f32_16x16x32_f16(ah[mt], bl, q1, 0, 0, 0);
            q1 = __builtin_amdgcn_mfma_f32_16x16x32_f16(al[mt], bh, q1, 0, 0, 0);
            q2 = __builtin_amdgcn_mfma_f32_16x16x32_f16(al[mt], bl, q2, 0, 0, 0);
            #pragma unroll
            for (int r = 0; r < 4; ++r) {
                const int m = mt * 16 + quad * 4 + r;
                float v = q0[r] + c1 * q1[r] + c2 * q2[r] + bv;
                v = fmaxf(v, 0.f);
                _Float16 t = (_Float16)v;
                h2h[cb * 1024 + m * 32 + cr] = t;
                h2l[cb * 1024 + m * 32 + cr] = (_Float16)((v - (float)t) * 2048.0f);
            }
        }
    }
    __syncthreads();

    // ---------------- phase 4: recon = h2 @ W4 + b4 (4-slot pairing) --------
    {
        _Float16* sBhi = R0h;                   // [4][4096]
        _Float16* sBlo = R0h + 4 * 4096;
        _Float16* h2h  = hP;
        _Float16* h2l  = hP + 8192;
        const int mt  = wv >> 3;                // 0..1 (row half)
        const int ntw = wv & 7;                 // 0..7 (col group)
        const int brow = tid >> 2;              // staging: tid<512 -> 0..127
        const int bk4  = (tid & 3) * 8;
        h8 rbh[2], rbl[2];                      // reg slots by step parity
        auto pf = [&](int ss) {
            if (tid < 512 && ss < 56) {
                int rg = (ss >> 3) * 128 + brow;
                if (rg > ND - 1) rg = ND - 1;
                const int k = (ss & 7) * 32 + bk4;
                rbh[ss & 1] = *(const h8*)(w4thi + (size_t)rg * NH + k);
                rbl[ss & 1] = *(const h8*)(w4tlo + (size_t)rg * NH + k);
            }
        };
        auto cm = [&](int ss) {
            if (tid < 512 && ss < 56) {
                const int sl = ss & 3;
                *(h8*)&sBhi[sl * 4096 + brow * 32 + bk4] = rbh[ss & 1];
                *(h8*)&sBlo[sl * 4096 + brow * 32 + bk4] = rbl[ss & 1];
            }
        };
        pf(0); pf(1); cm(0); cm(1); pf(2); pf(3);
        __syncthreads();

        f32x4 q0 = {}, q1 = {};
        auto step = [&](int t) {
            const int sl = t & 3, ks = t & 7;
            const int bo = sl * 4096 + (ntw * 16 + li) * 32 + kq;      // contig
            h8 fbh = *(const h8*)&sBhi[bo];
            h8 fbl = *(const h8*)&sBlo[bo];
            const int ao = ks * 1024 + (mt * 16 + li) * 32 + kq;       // contig
            h8 ah = *(const h8*)&h2h[ao];
            h8 al = *(const h8*)&h2l[ao];
            q0 = __builtin_amdgcn_mfma_f32_16x16x32_f16(ah, fbh, q0, 0, 0, 0);
            q1 = __builtin_amdgcn_mfma_f32_16x16x32_f16(ah, fbl, q1, 0, 0, 0);
            q1 = __builtin_amdgcn_mfma_f32_16x16x32_f16(al, fbh, q1, 0, 0, 0);
            if (ks == 7) {
                const int n = (t >> 3) * 128 + ntw * 16 + li;
                if (n < ND) {
                    const float bv = b4[n];
                    #pragma unroll
                    for (int r = 0; r < 4; ++r) {
                        const int m = mt * 16 + quad * 4 + r;
                        recon_g[(size_t)(r0 + m) * ND + n] = q0[r] + c1 * q1[r] + bv;
                    }
                }
                q0 = {}; q1 = {};
            }
        };
        for (int ii = 0; ii < 28; ++ii) {
            const int s0 = ii * 2;
            step(s0);
            step(s0 + 1);
            cm(s0 + 2); cm(s0 + 3);     // write slots not being read this interval
            pf(s0 + 4); pf(s0 + 5);
            __syncthreads();
        }
    }
    __syncthreads();

    // ---------------- phase 5: distances + stable softmin -------------------
    {
        float* tr0 = (float*)lds;               // [16][520] rows 0-15
        float* tr1 = (float*)(lds + 33280);     // [16][520] rows 16-31
        const int half = tid >> 9;              // 0: rows 0-15, 1: rows 16-31
        const int cl   = tid & 511;             // cluster id
        float* trh = half ? tr1 : tr0;
        const int rbase = half * 16;

        const float* rp = reps + (size_t)cl * NE;
        f32x4 rv[8];
        #pragma unroll
        for (int e4 = 0; e4 < 8; ++e4) rv[e4] = ((const f32x4*)rp)[e4];

        float d[16];
        #pragma unroll
        for (int r = 0; r < 16; ++r) {
            float a = 0.f;
            #pragma unroll
            for (int e4 = 0; e4 < 8; ++e4) {
                f32x4 ev = *(const f32x4*)&es[(rbase + r) * 36 + e4 * 4];  // broadcast
                #pragma unroll
                for (int j = 0; j < 4; ++j) {
                    float t = ev[j] - rv[e4][j];
                    a = fmaf(t, t, a);
                }
            }
            d[r] = a;
            trh[r * 520 + cl] = a;
        }
        __syncthreads();
        {   // min-reduce: wave handles 2 rows of its half; stride-64 scalar
            const int w8 = wv & 7;
            #pragma unroll
            for (int p = 0; p < 2; ++p) {
                const int rl = w8 * 2 + p;
                float m = trh[rl * 520 + lane];
                #pragma unroll
                for (int j = 1; j < 8; ++j)
                    m = fminf(m, trh[rl * 520 + lane + 64 * j]);
                #pragma unroll
                for (int off = 32; off > 0; off >>= 1)
                    m = fminf(m, __shfl_xor(m, off, 64));
                if (lane == 0) rmin[rbase + rl] = m;
            }
        }
        __syncthreads();
        #pragma unroll
        for (int r = 0; r < 16; ++r)
            trh[r * 520 + cl] = expf(-ALPHA_F * (d[r] - rmin[rbase + r]));
        __syncthreads();
        {   // sum-reduce
            const int w8 = wv & 7;
            #pragma unroll
            for (int p = 0; p < 2; ++p) {
                const int rl = w8 * 2 + p;
                float s = trh[rl * 520 + lane];
                #pragma unroll
                for (int j = 1; j < 8; ++j)
                    s += trh[rl * 520 + lane + 64 * j];
                #pragma unroll
                for (int off = 32; off > 0; off >>= 1)
                    s += __shfl_xor(s, off, 64);
                if (lane == 0) rinv[rbase + rl] = 1.0f / s;
            }
        }
        __syncthreads();
        #pragma unroll
        for (int r = 0; r < 16; ++r) {
            const size_t row = (size_t)(r0 + rbase + r);
            const float ev = trh[r * 520 + cl];      // exps still live in LDS
            dist_g[row * NK + cl] = d[r];
            wout_g[row * NK + cl] = d[r] * (ev * rinv[rbase + r]);
        }
    }
}

// ===========================================================================
// Fallback path (no/insufficient workspace): original verified 5-launch chain.
// ===========================================================================
__global__ __launch_bounds__(256)
void splitw2_kernel(const float* __restrict__ W1, _Float16* __restrict__ w1thi,
                    _Float16* __restrict__ w1tlo,
                    const float* __restrict__ W4, _Float16* __restrict__ w4thi,
                    _Float16* __restrict__ w4tlo) {
    const int b = blockIdx.x;
    const float* W; _Float16 *hi, *lo; int K, N, n;
    if (b < NH) { W = W1; hi = w1thi; lo = w1tlo; K = ND; N = NH; n = b; }
    else        { W = W4; hi = w4thi; lo = w4tlo; K = NH; N = ND; n = b - NH; }
    for (int k = threadIdx.x; k < K; k += 256) {
        float w = W[(size_t)k * N + n];
        _Float16 hh = (_Float16)w;
        float r = w - (float)hh;
        hi[(size_t)n * K + k] = hh;
        lo[(size_t)n * K + k] = (_Float16)(r * 2048.0f);
    }
}

template<int TERMS, bool RELU, bool SPLITA, int MT>
__global__ __launch_bounds__(256)
void mfma_gemm3(const float* __restrict__ Af32,
                const _Float16* __restrict__ Ahi_g,
                const _Float16* __restrict__ Alo_g,
                const _Float16* __restrict__ WThi,
                const _Float16* __restrict__ WTlo,
                const float* __restrict__ bias, float* __restrict__ C,
                int N, int K, int KS) {
    constexpr int BM  = MT * 32;
    constexpr int ACH = BM / 64;
    constexpr int AS  = BM * 40;
    constexpr int BS  = 64 * 40;
    __shared__ __align__(16) _Float16 smem[2 * BM * 40 * 2 + 2 * 64 * 40 * 2];
    _Float16* sAhi = smem;
    _Float16* sAlo = sAhi + 2 * BM * 40;
    _Float16* sBhi = sAlo + 2 * BM * 40;
    _Float16* sBlo = sBhi + 2 * 64 * 40;

    const int tid = threadIdx.x;
    const int bm  = blockIdx.x * BM;
    const int bn  = blockIdx.y * 64;

    const int arow = (ACH == 1) ? (tid >> 2) : (tid >> 1);
    const int ak   = (ACH == 1) ? ((tid & 3) * 8) : ((tid & 1) * 16);
    const int brow = tid >> 2;
    const int bk   = (tid & 3) * 8;

    const float*    pA32 = SPLITA ? Af32 + (size_t)(bm + arow) * K : nullptr;
    const _Float16* pAhi = SPLITA ? nullptr : Ahi_g + (size_t)(bm + arow) * K;
    const _Float16* pAlo = SPLITA ? nullptr : Alo_g + (size_t)(bm + arow) * K;
    int brow_g = bn + brow; if (brow_g > N - 1) brow_g = N - 1;
    const _Float16* pBhi = WThi + (size_t)brow_g * K;
    const _Float16* pBlo = WTlo + (size_t)brow_g * K;

    float araw[ACH * 8];
    h8 rahi[ACH], ralo[ACH];
    h8 rbhi, rblo;

    auto prefetch = [&](int s) {
        #pragma unroll
        for (int c = 0; c < ACH; ++c) {
            const int k = s * 32 + ak + c * 8;
            if (SPLITA) {
                if (k + 8 <= K) {
                    f32x4 v0 = *(const f32x4*)(pA32 + k);
                    f32x4 v1 = *(const f32x4*)(pA32 + k + 4);
                    #pragma unroll
                    for (int j = 0; j < 4; ++j) {
                        araw[c * 8 + j]     = v0[j];
                        araw[c * 8 + 4 + j] = v1[j];
                    }
                } else {
                    #pragma unroll
                    for (int j = 0; j < 8; ++j) araw[c * 8 + j] = 0.f;
                }
            } else {
                rahi[c] = (k + 8 <= K) ? *(const h8*)(pAhi + k) : (h8){};
                ralo[c] = (k + 8 <= K) ? *(const h8*)(pAlo + k) : (h8){};
            }
        }
        const int kb = s * 32 + bk;
        rbhi = (kb + 8 <= K) ? *(const h8*)(pBhi + kb) : (h8){};
        rblo = (kb + 8 <= K) ? *(const h8*)(pBlo + kb) : (h8){};
    };

    auto commit = [&](int buf) {
        #pragma unroll
        for (int c = 0; c < ACH; ++c) {
            h8 hi, lo;
            if (SPLITA) {
                #pragma unroll
                for (int j = 0; j < 8; ++j) {
                    float v = araw[c * 8 + j];
                    _Float16 hh = (_Float16)v;
                    hi[j] = hh;
                    lo[j] = (_Float16)((v - (float)hh) * 2048.0f);
                }
            } else { hi = rahi[c]; lo = ralo[c]; }
            *(h8*)&sAhi[buf * AS + arow * 40 + ak + c * 8] = hi;
            *(h8*)&sAlo[buf * AS + arow * 40 + ak + c * 8] = lo;
        }
        *(h8*)&sBhi[buf * BS + brow * 40 + bk] = rbhi;
        *(h8*)&sBlo[buf * BS + brow * 40 + bk] = rblo;
    };

    prefetch(0);
    commit(0);
    prefetch(1);
    __syncthreads();

    const int lane = tid & 63;
    const int wv   = tid >> 6;
    const int wm   = (wv >> 1) * (MT * 16);
    const int wn   = (wv & 1) * 32;
    const int li   = lane & 15;
    const int kq   = (lane >> 4) * 8;

    f32x4 acc0[MT][2] = {};
    f32x4 acc1[MT][2] = {};
    f32x4 acc2[MT][2] = {};

    for (int s = 0; s < KS; ++s) {
        const int buf = s & 1;
        h8 fahi[MT], falo[MT], fbhi[2], fblo[2];
        #pragma unroll
        for (int mt = 0; mt < MT; ++mt) {
            const int ao = buf * AS + (wm + mt * 16 + li) * 40 + kq;
            fahi[mt] = *(const h8*)&sAhi[ao];
            falo[mt] = *(const h8*)&sAlo[ao];
        }
        #pragma unroll
        for (int nt = 0; nt < 2; ++nt) {
            const int bo = buf * BS + (wn + nt * 16 + li) * 40 + kq;
            fbhi[nt] = *(const h8*)&sBhi[bo];
            fblo[nt] = *(const h8*)&sBlo[bo];
        }
        #pragma unroll
        for (int mt = 0; mt < MT; ++mt)
            #pragma unroll
            for (int nt = 0; nt < 2; ++nt) {
                acc0[mt][nt] = __builtin_amdgcn_mfma_f32_16x16x32_f16(
                    fahi[mt], fbhi[nt], acc0[mt][nt], 0, 0, 0);
                acc1[mt][nt] = __builtin_amdgcn_mfma_f32_16x16x32_f16(
                    fahi[mt], fblo[nt], acc1[mt][nt], 0, 0, 0);
                acc1[mt][nt] = __builtin_amdgcn_mfma_f32_16x16x32_f16(
                    falo[mt], fbhi[nt], acc1[mt][nt], 0, 0, 0);
                if (TERMS == 4)
                    acc2[mt][nt] = __builtin_amdgcn_mfma_f32_16x16x32_f16(
                        falo[mt], fblo[nt], acc2[mt][nt], 0, 0, 0);
            }
        if (s + 1 < KS) {
            commit((s + 1) & 1);
            if (s + 2 < KS) prefetch(s + 2);
        }
        __syncthreads();
    }

    const float c1 = 1.0f / 2048.0f;
    const float c2 = c1 * c1;
    const int quad = lane >> 4;
    #pragma unroll
    for (int nt = 0; nt < 2; ++nt) {
        const int n = bn + wn + nt * 16 + li;
        if (n < N) {
            const float bv = bias[n];
            #pragma unroll
            for (int mt = 0; mt < MT; ++mt) {
                #pragma unroll
                for (int r = 0; r < 4; ++r) {
                    const int m = bm + wm + mt * 16 + quad * 4 + r;
                    float v = acc0[mt][nt][r] + c1 * acc1[mt][nt][r];
                    if (TERMS == 4) v += c2 * acc2[mt][nt][r];
                    v += bv;
                    if (RELU) v = fmaxf(v, 0.f);
                    C[(size_t)m * N + n] = v;
                }
            }
        }
    }
}

__global__ __launch_bounds__(256)
void mid_kernel(const float* __restrict__ h, const float* __restrict__ W2,
                const float* __restrict__ b2, const float* __restrict__ W3,
                const float* __restrict__ b3, float* __restrict__ emb,
                _Float16* __restrict__ h2hi, _Float16* __restrict__ h2lo) {
    __shared__ float es[16][32];
    const int tid = threadIdx.x;
    const int r0  = blockIdx.x * 16;

    #pragma unroll
    for (int half = 0; half < 2; ++half) {
        const int o   = tid + half * 256;
        const int row = o >> 5;
        const int col = o & 31;
        const float* hrow = h + (size_t)(r0 + row) * NH;
        float acc0 = 0.f, acc1 = 0.f;
        #pragma unroll 4
        for (int k = 0; k < NH; k += 4) {
            float4 hv = *(const float4*)(hrow + k);
            acc0 = fmaf(hv.x, W2[(k + 0) * NE + col], acc0);
            acc1 = fmaf(hv.y, W2[(k + 1) * NE + col], acc1);
            acc0 = fmaf(hv.z, W2[(k + 2) * NE + col], acc0);
            acc1 = fmaf(hv.w, W2[(k + 3) * NE + col], acc1);
        }
        float v = acc0 + acc1 + b2[col];
        es[row][col] = v;
        emb[(size_t)r0 * NE + o] = v;
    }
    __syncthreads();

    const int col = tid;
    float acc[16];
    #pragma unroll
    for (int r = 0; r < 16; ++r) acc[r] = 0.f;
    #pragma unroll
    for (int k = 0; k < NE; ++k) {
        float w = W3[k * NH + col];
        #pragma unroll
        for (int r = 0; r < 16; ++r) acc[r] = fmaf(es[r][k], w, acc[r]);
    }
    const float bb = b3[col];
    #pragma unroll
    for (int r = 0; r < 16; ++r) {
        float v = acc[r] + bb;
        v = v > 0.f ? v : 0.f;
        _Float16 hh = (_Float16)v;
        float rr = v - (float)hh;
        h2hi[(size_t)(r0 + r) * NH + col] = hh;
        h2lo[(size_t)(r0 + r) * NH + col] = (_Float16)(rr * 2048.0f);
    }
}

__global__ __launch_bounds__(512, 4)
void dist_kernel(const float* __restrict__ emb, const float* __restrict__ reps,
                 float* __restrict__ dist, float* __restrict__ wout) {
    __shared__ float es[8][32];
    __shared__ float tr[8][520];
    __shared__ float rmin[8];
    __shared__ float rinv[8];

    const int tid = threadIdx.x;
    const int r0  = blockIdx.x * 8;

    if (tid < 256) es[tid >> 5][tid & 31] = emb[(size_t)r0 * NE + tid];

    const float* rp = reps + (size_t)tid * NE;
    f32x4 rv[8];
    #pragma unroll
    for (int e4 = 0; e4 < 8; ++e4) rv[e4] = ((const f32x4*)rp)[e4];
    __syncthreads();

    float d[8];
    #pragma unroll
    for (int r = 0; r < 8; ++r) {
        float a = 0.f;
        #pragma unroll
        for (int e4 = 0; e4 < 8; ++e4) {
            f32x4 ev = *(const f32x4*)&es[r][e4 * 4];
            #pragma unroll
            for (int j = 0; j < 4; ++j) {
                float t = ev[j] - rv[e4][j];
                a = fmaf(t, t, a);
            }
        }
        d[r] = a;
    }

    const int lane = tid & 63;
    const int wv   = tid >> 6;

    #pragma unroll
    for (int r = 0; r < 8; ++r) tr[r][tid] = d[r];
    __syncthreads();
    {
        f32x4 a = *(const f32x4*)&tr[wv][lane * 8];
        f32x4 b = *(const f32x4*)&tr[wv][lane * 8 + 4];
        float m = fminf(fminf(fminf(a[0], a[1]), fminf(a[2], a[3])),
                        fminf(fminf(b[0], b[1]), fminf(b[2], b[3])));
        #pragma unroll
        for (int off = 32; off > 0; off >>= 1)
            m = fminf(m, __shfl_xor(m, off, 64));
        if (lane == 0) rmin[wv] = m;
    }
    __syncthreads();

    float e[8];
    #pragma unroll
    for (int r = 0; r < 8; ++r) {
        e[r] = expf(-ALPHA_F * (d[r] - rmin[r]));
        tr[r][tid] = e[r];
    }
    __syncthreads();
    {
        f32x4 a = *(const f32x4*)&tr[wv][lane * 8];
        f32x4 b = *(const f32x4*)&tr[wv][lane * 8 + 4];
        float s = ((a[0] + a[1]) + (a[2] + a[3])) +
                  ((b[0] + b[1]) + (b[2] + b[3]));
        #pragma unroll
        for (int off = 32; off > 0; off >>= 1)
            s += __shfl_xor(s, off, 64);
        if (lane == 0) rinv[wv] = 1.0f / s;
    }
    __syncthreads();

    #pragma unroll
    for (int r = 0; r < 8; ++r) {
        const size_t row = (size_t)(r0 + r);
        dist[row * NK + tid] = d[r];
        wout[row * NK + tid] = d[r] * (e[r] * rinv[r]);
    }
}

// ---------------------------------------------------------------------------
extern "C" void kernel_launch(void* const* d_in, const int* in_sizes, int n_in,
                              void* d_out, int out_size, void* d_ws, size_t ws_size,
                              hipStream_t stream) {
    const float* x    = (const float*)d_in[0];
    const float* reps = (const float*)d_in[1];
    const float* W1   = (const float*)d_in[2];
    const float* b1   = (const float*)d_in[3];
    const float* W2   = (const float*)d_in[4];
    const float* b2   = (const float*)d_in[5];
    const float* W3   = (const float*)d_in[6];
    const float* b3   = (const float*)d_in[7];
    const float* W4   = (const float*)d_in[8];
    const float* b4   = (const float*)d_in[9];

    float* out   = (float*)d_out;
    float* wout  = out;                                          // [8192,512]
    float* dist  = out + (size_t)NB * NK;                        // [8192,512]
    float* recon = out + (size_t)2 * NB * NK;                    // [8192,784]
    float* emb   = out + (size_t)2 * NB * NK + (size_t)NB * ND;  // [8192,32]

    // Workspace: weight planes only (~1.7 MB): W1T, W4T, W2T, W3T hi/lo.
    const size_t nW14 = (size_t)ND * NH;     // 200704 halves per plane
    const size_t nW23 = (size_t)NE * NH;     // 8192 halves per plane
    const size_t wneed = (4 * nW14 + 4 * nW23) * sizeof(_Float16);

    if (d_ws != nullptr && ws_size >= wneed) {
        _Float16* w1thi = (_Float16*)d_ws;
        _Float16* w1tlo = w1thi + nW14;
        _Float16* w4thi = w1tlo + nW14;
        _Float16* w4tlo = w4thi + nW14;
        _Float16* w2thi = w4tlo + nW14;
        _Float16* w2tlo = w2thi + nW23;
        _Float16* w3thi = w2tlo + nW23;
        _Float16* w3tlo = w3thi + nW23;

        prep4_kernel<<<NBW1 + NBW4 + NBW2 + NBW3, 256, 0, stream>>>(
            W1, w1thi, w1tlo, W4, w4thi, w4tlo,
            W2, w2thi, w2tlo, W3, w3thi, w3tlo);

        mega_kernel<<<NB / 32, 1024, 0, stream>>>(
            x, reps, w1thi, w1tlo, w2thi, w2tlo, w3thi, w3tlo, w4thi, w4tlo,
            b1, b2, b3, b4, emb, recon, dist, wout);
    } else {
        // Fallback: original serialized 5-launch path with output-aliased
        // scratch (safe because launches are ordered).
        float* h = dist;
        _Float16* h2hi  = (_Float16*)(dist + (size_t)NB * NH);
        _Float16* h2lo  = h2hi + (size_t)NB * NH;
        _Float16* w1thi = (_Float16*)wout;
        _Float16* w1tlo = w1thi + (size_t)NH * ND;
        _Float16* w4thi = w1tlo + (size_t)NH * ND;
        _Float16* w4tlo = w4thi + (size_t)ND * NH;

        splitw2_kernel<<<NH + ND, 256, 0, stream>>>(W1, w1thi, w1tlo,
                                                    W4, w4thi, w4tlo);
        mfma_gemm3<4, true, true, 2><<<dim3(128, 4), 256, 0, stream>>>(
            x, nullptr, nullptr, w1thi, w1tlo, b1, h, NH, ND, 25);
        mid_kernel<<<NB / 16, 256, 0, stream>>>(h, W2, b2, W3, b3,
                                                emb, h2hi, h2lo);
        mfma_gemm3<3, false, false, 4><<<dim3(64, 13), 256, 0, stream>>>(
            nullptr, h2hi, h2lo, w4thi, w4tlo, b4, recon, ND, NH, 8);
        dist_kernel<<<NB / 8, 512, 0, stream>>>(emb, reps, dist, wout);
    }
}

// Round 10
// 151.947 us; speedup vs baseline: 1.0698x; 1.0428x over previous
//
#include <hip/hip_runtime.h>
#include <cstddef>

// Sizes (fixed per reference): B=8192, D=784, H=256, E=32, K=512
#define NB 8192
#define ND 784
#define NH 256
#define NE 32
#define NK 512
#define ALPHA_F 1000.0f

typedef _Float16 h8 __attribute__((ext_vector_type(8)));
typedef float f32x4 __attribute__((ext_vector_type(4)));

// ---------------------------------------------------------------------------
// prep4: W [K][N] fp32 -> WT hi/lo fp16 planes [N][K], via 32x32 LDS tiles.
// ---------------------------------------------------------------------------
#define TW1 25
#define TN1 8
#define NBW1 200        // W1 784x256
#define TW4 8
#define TN4 25
#define NBW4 200        // W4 256x784
#define NBW2 8          // W2 256x32
#define NBW3 8          // W3 32x256

__global__ __launch_bounds__(256)
void prep4_kernel(const float* __restrict__ W1, _Float16* __restrict__ w1thi,
                  _Float16* __restrict__ w1tlo,
                  const float* __restrict__ W4, _Float16* __restrict__ w4thi,
                  _Float16* __restrict__ w4tlo,
                  const float* __restrict__ W2, _Float16* __restrict__ w2thi,
                  _Float16* __restrict__ w2tlo,
                  const float* __restrict__ W3, _Float16* __restrict__ w3thi,
                  _Float16* __restrict__ w3tlo) {
    __shared__ float tile[32][33];
    const int b   = blockIdx.x;
    const int tid = threadIdx.x;

    const float* W; _Float16 *hi, *lo; int K, N, kt, nt;
    if (b < NBW1) {
        W = W1; hi = w1thi; lo = w1tlo; K = ND; N = NH;
        kt = b % TW1; nt = b / TW1;
    } else if (b < NBW1 + NBW4) {
        const int bb = b - NBW1;
        W = W4; hi = w4thi; lo = w4tlo; K = NH; N = ND;
        kt = bb % TW4; nt = bb / TW4;
    } else if (b < NBW1 + NBW4 + NBW2) {
        W = W2; hi = w2thi; lo = w2tlo; K = NH; N = NE;
        kt = b - (NBW1 + NBW4); nt = 0;
    } else {
        W = W3; hi = w3thi; lo = w3tlo; K = NE; N = NH;
        kt = 0; nt = b - (NBW1 + NBW4 + NBW2);
    }
    const int k0 = kt * 32, n0 = nt * 32;
    const int row = tid >> 3, c4 = (tid & 7) * 4;
    #pragma unroll
    for (int j = 0; j < 4; ++j) {
        const int k = k0 + row, n = n0 + c4 + j;
        tile[row][c4 + j] = (k < K && n < N) ? W[(size_t)k * N + n] : 0.f;
    }
    __syncthreads();
    const int n = n0 + row;
    if (n < N) {
        #pragma unroll
        for (int j = 0; j < 4; ++j) {
            const int k = k0 + c4 + j;
            if (k < K) {
                float w = tile[c4 + j][row];
                _Float16 hh = (_Float16)w;
                float r = w - (float)hh;
                hi[(size_t)n * K + k] = hh;
                lo[(size_t)n * K + k] = (_Float16)(r * 2048.0f);
            }
        }
    }
}

// ---------------------------------------------------------------------------
// MEGA v6 = v5 + SINGLE-PLANE RECON PATH. The softmin path (x->h->emb) keeps
// split-fp16 (ALPHA=1000 amplifies emb error by e^(1000*d_err)); the recon
// path (h2, W4) is plain fp16: recon |.|~0.06, fp16 error ~1e-4 << margin.
// ph3: 1 MFMA (ehi@W3hi), h2 stored as ONE plane.
// ph4: 1 B commit + 1 B read + 1 A read + 1 MFMA per step (was 2/2/2/3) ->
//      interval LDS traffic ~52KB vs 150KB (kernel is LDS-BW-bound, R9).
// 1024 threads (16 waves), conflict-free [ks][row][32] layouts (v5).
// ---------------------------------------------------------------------------
__global__ __launch_bounds__(1024, 4)
void mega_kernel(const float* __restrict__ x, const float* __restrict__ reps,
                 const _Float16* __restrict__ w1thi, const _Float16* __restrict__ w1tlo,
                 const _Float16* __restrict__ w2thi, const _Float16* __restrict__ w2tlo,
                 const _Float16* __restrict__ w3thi, const _Float16* __restrict__ w3tlo,
                 const _Float16* __restrict__ w4thi, const _Float16* __restrict__ w4tlo,
                 const float* __restrict__ b1, const float* __restrict__ b2,
                 const float* __restrict__ b3, const float* __restrict__ b4,
                 float* __restrict__ emb_g, float* __restrict__ recon_g,
                 float* __restrict__ dist_g, float* __restrict__ wout_g) {
    // LDS map (bytes) — same as v5:
    // [0,66560)       R0: ph1 sB dbuf | ph2 W2 | ph3 W3hi | ph4 sB 4-slot |
    //                 ph5 tr0 [16][520]f @0 + tr1 @33280
    // [66560,74752)   sA dbuf [2][1024]h x2
    // [74752,107520)  h planes x2 (ph1-2) / h2 single plane (ph3-4)
    // [107520,112128) es f32 [32][36]
    // [112128,116224) emb planes [32][32]h x2
    // [116224,116480) rmin[32], rinv[32]
    __shared__ __align__(16) unsigned char lds[116480];
    _Float16* R0h  = (_Float16*)lds;
    _Float16* sA   = (_Float16*)(lds + 66560);
    _Float16* hP   = (_Float16*)(lds + 74752);
    float*    es   = (float*)(lds + 107520);
    _Float16* eP   = (_Float16*)(lds + 112128);
    float*    rmin = (float*)(lds + 116224);
    float*    rinv = (float*)(lds + 116352);

    const int tid  = threadIdx.x;
    const int lane = tid & 63;
    const int wv   = tid >> 6;          // 0..15
    const int li   = lane & 15;
    const int kq   = (lane >> 4) * 8;
    const int quad = lane >> 4;
    const int r0   = blockIdx.x * 32;

    const float c1 = 1.0f / 2048.0f;
    const float c2 = c1 * c1;

    // ---------------- phase 1: h planes = split(relu(x @ W1 + b1)) ----------
    {
        _Float16* sBhi = R0h;                   // [2][8192]
        _Float16* sBlo = R0h + 2 * 8192;
        _Float16* sAhi = sA;                    // [2][1024]
        _Float16* sAlo = sA + 2 * 1024;
        const int aro  = tid >> 2;              // A: tid<128 -> rows 0..31
        const int ak   = (tid & 3) * 8;
        const int brow = tid >> 2;              // B: 0..255
        const int bk   = (tid & 3) * 8;
        const float*    pA  = x + (size_t)(r0 + aro) * ND;
        const _Float16* pBh = w1thi + (size_t)brow * ND;
        const _Float16* pBl = w1tlo + (size_t)brow * ND;

        float araw[8];
        h8 rbh, rbl;

        auto pf = [&](int s) {
            if (tid < 128) {
                const int k = s * 32 + ak;
                if (k + 8 <= ND) {
                    f32x4 v0 = *(const f32x4*)(pA + k);
                    f32x4 v1 = *(const f32x4*)(pA + k + 4);
                    #pragma unroll
                    for (int j = 0; j < 4; ++j) {
                        araw[j] = v0[j]; araw[4 + j] = v1[j];
                    }
                } else {
                    #pragma unroll
                    for (int j = 0; j < 8; ++j) araw[j] = 0.f;
                }
            }
            const int kb = s * 32 + bk;
            rbh = (kb + 8 <= ND) ? *(const h8*)(pBh + kb) : (h8){};
            rbl = (kb + 8 <= ND) ? *(const h8*)(pBl + kb) : (h8){};
        };
        auto cm = [&](int buf) {
            if (tid < 128) {
                h8 hi, lo;
                #pragma unroll
                for (int j = 0; j < 8; ++j) {
                    float v = araw[j];
                    _Float16 hh = (_Float16)v;
                    hi[j] = hh;
                    lo[j] = (_Float16)((v - (float)hh) * 2048.0f);
                }
                *(h8*)&sAhi[buf * 1024 + aro * 32 + ak] = hi;   // 16*tid contig
                *(h8*)&sAlo[buf * 1024 + aro * 32 + ak] = lo;
            }
            *(h8*)&sBhi[buf * 8192 + brow * 32 + bk] = rbh;     // 16*tid contig
            *(h8*)&sBlo[buf * 8192 + brow * 32 + bk] = rbl;
        };

        pf(0); cm(0); pf(1);
        __syncthreads();

        f32x4 a0[2] = {}, a1[2] = {}, a2[2] = {};
        for (int s = 0; s < 25; ++s) {
            const int buf = s & 1;
            h8 fah[2], fal[2];
            #pragma unroll
            for (int mt = 0; mt < 2; ++mt) {
                const int ao = buf * 1024 + (mt * 16 + li) * 32 + kq;  // contig 1KB
                fah[mt] = *(const h8*)&sAhi[ao];
                fal[mt] = *(const h8*)&sAlo[ao];
            }
            const int bo = buf * 8192 + (wv * 16 + li) * 32 + kq;      // contig 1KB
            h8 fbh = *(const h8*)&sBhi[bo];
            h8 fbl = *(const h8*)&sBlo[bo];
            #pragma unroll
            for (int mt = 0; mt < 2; ++mt) {
                a0[mt] = __builtin_amdgcn_mfma_f32_16x16x32_f16(fah[mt], fbh, a0[mt], 0, 0, 0);
                a1[mt] = __builtin_amdgcn_mfma_f32_16x16x32_f16(fah[mt], fbl, a1[mt], 0, 0, 0);
                a1[mt] = __builtin_amdgcn_mfma_f32_16x16x32_f16(fal[mt], fbh, a1[mt], 0, 0, 0);
                a2[mt] = __builtin_amdgcn_mfma_f32_16x16x32_f16(fal[mt], fbl, a2[mt], 0, 0, 0);
            }
            if (s + 1 < 25) { cm((s + 1) & 1); if (s + 2 < 25) pf(s + 2); }
            __syncthreads();
        }
        // epilogue -> h planes [8][32][32]
        _Float16* hhi = hP;
        _Float16* hlo = hP + 8192;
        const int n  = wv * 16 + li;
        const int nb = n >> 5, nr = n & 31;
        const float bv = b1[n];
        #pragma unroll
        for (int mt = 0; mt < 2; ++mt)
            #pragma unroll
            for (int r = 0; r < 4; ++r) {
                const int m = mt * 16 + quad * 4 + r;
                float v = a0[mt][r] + c1 * a1[mt][r] + c2 * a2[mt][r] + bv;
                v = fmaxf(v, 0.f);
                _Float16 t = (_Float16)v;
                hhi[nb * 1024 + m * 32 + nr] = t;
                hlo[nb * 1024 + m * 32 + nr] = (_Float16)((v - (float)t) * 2048.0f);
            }
    }
    __syncthreads();

    // ---------------- phase 2: emb = h @ W2 + b2 (full split, critical) -----
    {   // stage W2T planes [32 col][256 k] -> LDS [8 ks][32 col][32]
        _Float16* w2h = R0h;                    // [8192]
        _Float16* w2l = R0h + 8192;
        const int col = tid >> 5;               // 0..31
        const int k8  = tid & 31;               // h8 chunk 0..31
        const int src = col * 256 + k8 * 8;
        const int dst = (k8 >> 2) * 1024 + col * 32 + (k8 & 3) * 8;
        *(h8*)&w2h[dst] = *(const h8*)(w2thi + src);
        *(h8*)&w2l[dst] = *(const h8*)(w2tlo + src);
    }
    __syncthreads();
    if (wv < 4) {
        const int mt = wv >> 1, nt = wv & 1;
        _Float16* hhi = hP;
        _Float16* hlo = hP + 8192;
        _Float16* w2h = R0h;
        _Float16* w2l = R0h + 8192;
        f32x4 e0 = {}, e1 = {}, e2 = {};
        #pragma unroll
        for (int ks = 0; ks < 8; ++ks) {
            h8 ah = *(const h8*)&hhi[ks * 1024 + (mt * 16 + li) * 32 + kq];
            h8 al = *(const h8*)&hlo[ks * 1024 + (mt * 16 + li) * 32 + kq];
            h8 bh = *(const h8*)&w2h[ks * 1024 + (nt * 16 + li) * 32 + kq];
            h8 bl = *(const h8*)&w2l[ks * 1024 + (nt * 16 + li) * 32 + kq];
            e0 = __builtin_amdgcn_mfma_f32_16x16x32_f16(ah, bh, e0, 0, 0, 0);
            e1 = __builtin_amdgcn_mfma_f32_16x16x32_f16(ah, bl, e1, 0, 0, 0);
            e1 = __builtin_amdgcn_mfma_f32_16x16x32_f16(al, bh, e1, 0, 0, 0);
            e2 = __builtin_amdgcn_mfma_f32_16x16x32_f16(al, bl, e2, 0, 0, 0);
        }
        const int col = nt * 16 + li;
        const float bv = b2[col];
        _Float16* eh = eP;                      // [32][32]
        _Float16* el = eP + 1024;
        #pragma unroll
        for (int r = 0; r < 4; ++r) {
            const int m = mt * 16 + quad * 4 + r;
            float v = e0[r] + c1 * e1[r] + c2 * e2[r] + bv;
            es[m * 36 + col] = v;
            _Float16 t = (_Float16)v;
            eh[m * 32 + col] = t;
            el[m * 32 + col] = (_Float16)((v - (float)t) * 2048.0f);
            emb_g[(size_t)(r0 + m) * NE + col] = v;
        }
    }
    __syncthreads();

    // ---------------- phase 3: h2 = relu(emb @ W3 + b3), plain fp16 ---------
    {   // stage W3T hi plane only [256][32] (contiguous copy: 1024 chunks)
        _Float16* w3h = R0h;
        const int o = tid * 8;
        *(h8*)&w3h[o] = *(const h8*)(w3thi + o);
    }
    __syncthreads();
    {
        _Float16* w3h  = R0h;
        _Float16* h2h  = hP;                    // SINGLE plane (overlays h)
        _Float16* eh   = eP;
        h8 ah[2];
        #pragma unroll
        for (int mt = 0; mt < 2; ++mt)
            ah[mt] = *(const h8*)&eh[(mt * 16 + li) * 32 + kq];
        const int col = wv * 16 + li;
        h8 bh = *(const h8*)&w3h[col * 32 + kq];
        const float bv = b3[col];
        const int cb = col >> 5, cr = col & 31;
        #pragma unroll
        for (int mt = 0; mt < 2; ++mt) {
            f32x4 q0 = {};
            q0 = __builtin_amdgcn_mfma_f32_16x16x32_f16(ah[mt], bh, q0, 0, 0, 0);
            #pragma unroll
            for (int r = 0; r < 4; ++r) {
                const int m = mt * 16 + quad * 4 + r;
                float v = q0[r] + bv;
                v = fmaxf(v, 0.f);
                h2h[cb * 1024 + m * 32 + cr] = (_Float16)v;
            }
        }
    }
    __syncthreads();

    // ---------------- phase 4: recon = h2 @ W4 + b4, plain fp16, 4-slot -----
    {
        _Float16* sBhi = R0h;                   // [4][4096] single plane
        _Float16* h2h  = hP;
        const int mt  = wv >> 3;                // 0..1 (row half)
        const int ntw = wv & 7;                 // 0..7 (col group)
        const int brow = tid >> 2;              // staging: tid<512 -> 0..127
        const int bk4  = (tid & 3) * 8;
        h8 rbh[2];                              // reg slots by step parity
        auto pf = [&](int ss) {
            if (tid < 512 && ss < 56) {
                int rg = (ss >> 3) * 128 + brow;
                if (rg > ND - 1) rg = ND - 1;
                const int k = (ss & 7) * 32 + bk4;
                rbh[ss & 1] = *(const h8*)(w4thi + (size_t)rg * NH + k);
            }
        };
        auto cm = [&](int ss) {
            if (tid < 512 && ss < 56) {
                const int sl = ss & 3;
                *(h8*)&sBhi[sl * 4096 + brow * 32 + bk4] = rbh[ss & 1];
            }
        };
        pf(0); pf(1); cm(0); cm(1); pf(2); pf(3);
        __syncthreads();

        f32x4 q0 = {};
        auto step = [&](int t) {
            const int sl = t & 3, ks = t & 7;
            const int bo = sl * 4096 + (ntw * 16 + li) * 32 + kq;      // contig
            h8 fbh = *(const h8*)&sBhi[bo];
            const int ao = ks * 1024 + (mt * 16 + li) * 32 + kq;       // contig
            h8 ah = *(const h8*)&h2h[ao];
            q0 = __builtin_amdgcn_mfma_f32_16x16x32_f16(ah, fbh, q0, 0, 0, 0);
            if (ks == 7) {
                const int n = (t >> 3) * 128 + ntw * 16 + li;
                if (n < ND) {
                    const float bv = b4[n];
                    #pragma unroll
                    for (int r = 0; r < 4; ++r) {
                        const int m = mt * 16 + quad * 4 + r;
                        recon_g[(size_t)(r0 + m) * ND + n] = q0[r] + bv;
                    }
                }
                q0 = {};
            }
        };
        for (int ii = 0; ii < 28; ++ii) {
            const int s0 = ii * 2;
            step(s0);
            step(s0 + 1);
            cm(s0 + 2); cm(s0 + 3);     // write slots not being read this interval
            pf(s0 + 4); pf(s0 + 5);
            __syncthreads();
        }
    }
    __syncthreads();

    // ---------------- phase 5: distances + stable softmin -------------------
    {
        float* tr0 = (float*)lds;               // [16][520] rows 0-15
        float* tr1 = (float*)(lds + 33280);     // [16][520] rows 16-31
        const int half = tid >> 9;              // 0: rows 0-15, 1: rows 16-31
        const int cl   = tid & 511;             // cluster id
        float* trh = half ? tr1 : tr0;
        const int rbase = half * 16;

        const float* rp = reps + (size_t)cl * NE;
        f32x4 rv[8];
        #pragma unroll
        for (int e4 = 0; e4 < 8; ++e4) rv[e4] = ((const f32x4*)rp)[e4];

        float d[16];
        #pragma unroll
        for (int r = 0; r < 16; ++r) {
            float a = 0.f;
            #pragma unroll
            for (int e4 = 0; e4 < 8; ++e4) {
                f32x4 ev = *(const f32x4*)&es[(rbase + r) * 36 + e4 * 4];  // broadcast
                #pragma unroll
                for (int j = 0; j < 4; ++j) {
                    float t = ev[j] - rv[e4][j];
                    a = fmaf(t, t, a);
                }
            }
            d[r] = a;
            trh[r * 520 + cl] = a;
        }
        __syncthreads();
        {   // min-reduce: wave handles 2 rows of its half; stride-64 scalar
            const int w8 = wv & 7;
            #pragma unroll
            for (int p = 0; p < 2; ++p) {
                const int rl = w8 * 2 + p;
                float m = trh[rl * 520 + lane];
                #pragma unroll
                for (int j = 1; j < 8; ++j)
                    m = fminf(m, trh[rl * 520 + lane + 64 * j]);
                #pragma unroll
                for (int off = 32; off > 0; off >>= 1)
                    m = fminf(m, __shfl_xor(m, off, 64));
                if (lane == 0) rmin[rbase + rl] = m;
            }
        }
        __syncthreads();
        #pragma unroll
        for (int r = 0; r < 16; ++r)
            trh[r * 520 + cl] = expf(-ALPHA_F * (d[r] - rmin[rbase + r]));
        __syncthreads();
        {   // sum-reduce
            const int w8 = wv & 7;
            #pragma unroll
            for (int p = 0; p < 2; ++p) {
                const int rl = w8 * 2 + p;
                float s = trh[rl * 520 + lane];
                #pragma unroll
                for (int j = 1; j < 8; ++j)
                    s += trh[rl * 520 + lane + 64 * j];
                #pragma unroll
                for (int off = 32; off > 0; off >>= 1)
                    s += __shfl_xor(s, off, 64);
                if (lane == 0) rinv[rbase + rl] = 1.0f / s;
            }
        }
        __syncthreads();
        #pragma unroll
        for (int r = 0; r < 16; ++r) {
            const size_t row = (size_t)(r0 + rbase + r);
            const float ev = trh[r * 520 + cl];      // exps still live in LDS
            dist_g[row * NK + cl] = d[r];
            wout_g[row * NK + cl] = d[r] * (ev * rinv[rbase + r]);
        }
    }
}

// ===========================================================================
// Fallback path (no/insufficient workspace): original verified 5-launch chain.
// ===========================================================================
__global__ __launch_bounds__(256)
void splitw2_kernel(const float* __restrict__ W1, _Float16* __restrict__ w1thi,
                    _Float16* __restrict__ w1tlo,
                    const float* __restrict__ W4, _Float16* __restrict__ w4thi,
                    _Float16* __restrict__ w4tlo) {
    const int b = blockIdx.x;
    const float* W; _Float16 *hi, *lo; int K, N, n;
    if (b < NH) { W = W1; hi = w1thi; lo = w1tlo; K = ND; N = NH; n = b; }
    else        { W = W4; hi = w4thi; lo = w4tlo; K = NH; N = ND; n = b - NH; }
    for (int k = threadIdx.x; k < K; k += 256) {
        float w = W[(size_t)k * N + n];
        _Float16 hh = (_Float16)w;
        float r = w - (float)hh;
        hi[(size_t)n * K + k] = hh;
        lo[(size_t)n * K + k] = (_Float16)(r * 2048.0f);
    }
}

template<int TERMS, bool RELU, bool SPLITA, int MT>
__global__ __launch_bounds__(256)
void mfma_gemm3(const float* __restrict__ Af32,
                const _Float16* __restrict__ Ahi_g,
                const _Float16* __restrict__ Alo_g,
                const _Float16* __restrict__ WThi,
                const _Float16* __restrict__ WTlo,
                const float* __restrict__ bias, float* __restrict__ C,
                int N, int K, int KS) {
    constexpr int BM  = MT * 32;
    constexpr int ACH = BM / 64;
    constexpr int AS  = BM * 40;
    constexpr int BS  = 64 * 40;
    __shared__ __align__(16) _Float16 smem[2 * BM * 40 * 2 + 2 * 64 * 40 * 2];
    _Float16* sAhi = smem;
    _Float16* sAlo = sAhi + 2 * BM * 40;
    _Float16* sBhi = sAlo + 2 * BM * 40;
    _Float16* sBlo = sBhi + 2 * 64 * 40;

    const int tid = threadIdx.x;
    const int bm  = blockIdx.x * BM;
    const int bn  = blockIdx.y * 64;

    const int arow = (ACH == 1) ? (tid >> 2) : (tid >> 1);
    const int ak   = (ACH == 1) ? ((tid & 3) * 8) : ((tid & 1) * 16);
    const int brow = tid >> 2;
    const int bk   = (tid & 3) * 8;

    const float*    pA32 = SPLITA ? Af32 + (size_t)(bm + arow) * K : nullptr;
    const _Float16* pAhi = SPLITA ? nullptr : Ahi_g + (size_t)(bm + arow) * K;
    const _Float16* pAlo = SPLITA ? nullptr : Alo_g + (size_t)(bm + arow) * K;
    int brow_g = bn + brow; if (brow_g > N - 1) brow_g = N - 1;
    const _Float16* pBhi = WThi + (size_t)brow_g * K;
    const _Float16* pBlo = WTlo + (size_t)brow_g * K;

    float araw[ACH * 8];
    h8 rahi[ACH], ralo[ACH];
    h8 rbhi, rblo;

    auto prefetch = [&](int s) {
        #pragma unroll
        for (int c = 0; c < ACH; ++c) {
            const int k = s * 32 + ak + c * 8;
            if (SPLITA) {
                if (k + 8 <= K) {
                    f32x4 v0 = *(const f32x4*)(pA32 + k);
                    f32x4 v1 = *(const f32x4*)(pA32 + k + 4);
                    #pragma unroll
                    for (int j = 0; j < 4; ++j) {
                        araw[c * 8 + j]     = v0[j];
                        araw[c * 8 + 4 + j] = v1[j];
                    }
                } else {
                    #pragma unroll
                    for (int j = 0; j < 8; ++j) araw[c * 8 + j] = 0.f;
                }
            } else {
                rahi[c] = (k + 8 <= K) ? *(const h8*)(pAhi + k) : (h8){};
                ralo[c] = (k + 8 <= K) ? *(const h8*)(pAlo + k) : (h8){};
            }
        }
        const int kb = s * 32 + bk;
        rbhi = (kb + 8 <= K) ? *(const h8*)(pBhi + kb) : (h8){};
        rblo = (kb + 8 <= K) ? *(const h8*)(pBlo + kb) : (h8){};
    };

    auto commit = [&](int buf) {
        #pragma unroll
        for (int c = 0; c < ACH; ++c) {
            h8 hi, lo;
            if (SPLITA) {
                #pragma unroll
                for (int j = 0; j < 8; ++j) {
                    float v = araw[c * 8 + j];
                    _Float16 hh = (_Float16)v;
                    hi[j] = hh;
                    lo[j] = (_Float16)((v - (float)hh) * 2048.0f);
                }
            } else { hi = rahi[c]; lo = ralo[c]; }
            *(h8*)&sAhi[buf * AS + arow * 40 + ak + c * 8] = hi;
            *(h8*)&sAlo[buf * AS + arow * 40 + ak + c * 8] = lo;
        }
        *(h8*)&sBhi[buf * BS + brow * 40 + bk] = rbhi;
        *(h8*)&sBlo[buf * BS + brow * 40 + bk] = rblo;
    };

    prefetch(0);
    commit(0);
    prefetch(1);
    __syncthreads();

    const int lane = tid & 63;
    const int wv   = tid >> 6;
    const int wm   = (wv >> 1) * (MT * 16);
    const int wn   = (wv & 1) * 32;
    const int li   = lane & 15;
    const int kq   = (lane >> 4) * 8;

    f32x4 acc0[MT][2] = {};
    f32x4 acc1[MT][2] = {};
    f32x4 acc2[MT][2] = {};

    for (int s = 0; s < KS; ++s) {
        const int buf = s & 1;
        h8 fahi[MT], falo[MT], fbhi[2], fblo[2];
        #pragma unroll
        for (int mt = 0; mt < MT; ++mt) {
            const int ao = buf * AS + (wm + mt * 16 + li) * 40 + kq;
            fahi[mt] = *(const h8*)&sAhi[ao];
            falo[mt] = *(const h8*)&sAlo[ao];
        }
        #pragma unroll
        for (int nt = 0; nt < 2; ++nt) {
            const int bo = buf * BS + (wn + nt * 16 + li) * 40 + kq;
            fbhi[nt] = *(const h8*)&sBhi[bo];
            fblo[nt] = *(const h8*)&sBlo[bo];
        }
        #pragma unroll
        for (int mt = 0; mt < MT; ++mt)
            #pragma unroll
            for (int nt = 0; nt < 2; ++nt) {
                acc0[mt][nt] = __builtin_amdgcn_mfma_f32_16x16x32_f16(
                    fahi[mt], fbhi[nt], acc0[mt][nt], 0, 0, 0);
                acc1[mt][nt] = __builtin_amdgcn_mfma_f32_16x16x32_f16(
                    fahi[mt], fblo[nt], acc1[mt][nt], 0, 0, 0);
                acc1[mt][nt] = __builtin_amdgcn_mfma_f32_16x16x32_f16(
                    falo[mt], fbhi[nt], acc1[mt][nt], 0, 0, 0);
                if (TERMS == 4)
                    acc2[mt][nt] = __builtin_amdgcn_mfma_f32_16x16x32_f16(
                        falo[mt], fblo[nt], acc2[mt][nt], 0, 0, 0);
            }
        if (s + 1 < KS) {
            commit((s + 1) & 1);
            if (s + 2 < KS) prefetch(s + 2);
        }
        __syncthreads();
    }

    const float c1 = 1.0f / 2048.0f;
    const float c2 = c1 * c1;
    const int quad = lane >> 4;
    #pragma unroll
    for (int nt = 0; nt < 2; ++nt) {
        const int n = bn + wn + nt * 16 + li;
        if (n < N) {
            const float bv = bias[n];
            #pragma unroll
            for (int mt = 0; mt < MT; ++mt) {
                #pragma unroll
                for (int r = 0; r < 4; ++r) {
                    const int m = bm + wm + mt * 16 + quad * 4 + r;
                    float v = acc0[mt][nt][r] + c1 * acc1[mt][nt][r];
                    if (TERMS == 4) v += c2 * acc2[mt][nt][r];
                    v += bv;
                    if (RELU) v = fmaxf(v, 0.f);
                    C[(size_t)m * N + n] = v;
                }
            }
        }
    }
}

__global__ __launch_bounds__(256)
void mid_kernel(const float* __restrict__ h, const float* __restrict__ W2,
                const float* __restrict__ b2, const float* __restrict__ W3,
                const float* __restrict__ b3, float* __restrict__ emb,
                _Float16* __restrict__ h2hi, _Float16* __restrict__ h2lo) {
    __shared__ float es[16][32];
    const int tid = threadIdx.x;
    const int r0  = blockIdx.x * 16;

    #pragma unroll
    for (int half = 0; half < 2; ++half) {
        const int o   = tid + half * 256;
        const int row = o >> 5;
        const int col = o & 31;
        const float* hrow = h + (size_t)(r0 + row) * NH;
        float acc0 = 0.f, acc1 = 0.f;
        #pragma unroll 4
        for (int k = 0; k < NH; k += 4) {
            float4 hv = *(const float4*)(hrow + k);
            acc0 = fmaf(hv.x, W2[(k + 0) * NE + col], acc0);
            acc1 = fmaf(hv.y, W2[(k + 1) * NE + col], acc1);
            acc0 = fmaf(hv.z, W2[(k + 2) * NE + col], acc0);
            acc1 = fmaf(hv.w, W2[(k + 3) * NE + col], acc1);
        }
        float v = acc0 + acc1 + b2[col];
        es[row][col] = v;
        emb[(size_t)r0 * NE + o] = v;
    }
    __syncthreads();

    const int col = tid;
    float acc[16];
    #pragma unroll
    for (int r = 0; r < 16; ++r) acc[r] = 0.f;
    #pragma unroll
    for (int k = 0; k < NE; ++k) {
        float w = W3[k * NH + col];
        #pragma unroll
        for (int r = 0; r < 16; ++r) acc[r] = fmaf(es[r][k], w, acc[r]);
    }
    const float bb = b3[col];
    #pragma unroll
    for (int r = 0; r < 16; ++r) {
        float v = acc[r] + bb;
        v = v > 0.f ? v : 0.f;
        _Float16 hh = (_Float16)v;
        float rr = v - (float)hh;
        h2hi[(size_t)(r0 + r) * NH + col] = hh;
        h2lo[(size_t)(r0 + r) * NH + col] = (_Float16)(rr * 2048.0f);
    }
}

__global__ __launch_bounds__(512, 4)
void dist_kernel(const float* __restrict__ emb, const float* __restrict__ reps,
                 float* __restrict__ dist, float* __restrict__ wout) {
    __shared__ float es[8][32];
    __shared__ float tr[8][520];
    __shared__ float rmin[8];
    __shared__ float rinv[8];

    const int tid = threadIdx.x;
    const int r0  = blockIdx.x * 8;

    if (tid < 256) es[tid >> 5][tid & 31] = emb[(size_t)r0 * NE + tid];

    const float* rp = reps + (size_t)tid * NE;
    f32x4 rv[8];
    #pragma unroll
    for (int e4 = 0; e4 < 8; ++e4) rv[e4] = ((const f32x4*)rp)[e4];
    __syncthreads();

    float d[8];
    #pragma unroll
    for (int r = 0; r < 8; ++r) {
        float a = 0.f;
        #pragma unroll
        for (int e4 = 0; e4 < 8; ++e4) {
            f32x4 ev = *(const f32x4*)&es[r][e4 * 4];
            #pragma unroll
            for (int j = 0; j < 4; ++j) {
                float t = ev[j] - rv[e4][j];
                a = fmaf(t, t, a);
            }
        }
        d[r] = a;
    }

    const int lane = tid & 63;
    const int wv   = tid >> 6;

    #pragma unroll
    for (int r = 0; r < 8; ++r) tr[r][tid] = d[r];
    __syncthreads();
    {
        f32x4 a = *(const f32x4*)&tr[wv][lane * 8];
        f32x4 b = *(const f32x4*)&tr[wv][lane * 8 + 4];
        float m = fminf(fminf(fminf(a[0], a[1]), fminf(a[2], a[3])),
                        fminf(fminf(b[0], b[1]), fminf(b[2], b[3])));
        #pragma unroll
        for (int off = 32; off > 0; off >>= 1)
            m = fminf(m, __shfl_xor(m, off, 64));
        if (lane == 0) rmin[wv] = m;
    }
    __syncthreads();

    float e[8];
    #pragma unroll
    for (int r = 0; r < 8; ++r) {
        e[r] = expf(-ALPHA_F * (d[r] - rmin[r]));
        tr[r][tid] = e[r];
    }
    __syncthreads();
    {
        f32x4 a = *(const f32x4*)&tr[wv][lane * 8];
        f32x4 b = *(const f32x4*)&tr[wv][lane * 8 + 4];
        float s = ((a[0] + a[1]) + (a[2] + a[3])) +
                  ((b[0] + b[1]) + (b[2] + b[3]));
        #pragma unroll
        for (int off = 32; off > 0; off >>= 1)
            s += __shfl_xor(s, off, 64);
        if (lane == 0) rinv[wv] = 1.0f / s;
    }
    __syncthreads();

    #pragma unroll
    for (int r = 0; r < 8; ++r) {
        const size_t row = (size_t)(r0 + r);
        dist[row * NK + tid] = d[r];
        wout[row * NK + tid] = d[r] * (e[r] * rinv[r]);
    }
}

// ---------------------------------------------------------------------------
extern "C" void kernel_launch(void* const* d_in, const int* in_sizes, int n_in,
                              void* d_out, int out_size, void* d_ws, size_t ws_size,
                              hipStream_t stream) {
    const float* x    = (const float*)d_in[0];
    const float* reps = (const float*)d_in[1];
    const float* W1   = (const float*)d_in[2];
    const float* b1   = (const float*)d_in[3];
    const float* W2   = (const float*)d_in[4];
    const float* b2   = (const float*)d_in[5];
    const float* W3   = (const float*)d_in[6];
    const float* b3   = (const float*)d_in[7];
    const float* W4   = (const float*)d_in[8];
    const float* b4   = (const float*)d_in[9];

    float* out   = (float*)d_out;
    float* wout  = out;                                          // [8192,512]
    float* dist  = out + (size_t)NB * NK;                        // [8192,512]
    float* recon = out + (size_t)2 * NB * NK;                    // [8192,784]
    float* emb   = out + (size_t)2 * NB * NK + (size_t)NB * ND;  // [8192,32]

    // Workspace: weight planes only (~1.7 MB): W1T, W4T, W2T, W3T hi/lo.
    const size_t nW14 = (size_t)ND * NH;     // 200704 halves per plane
    const size_t nW23 = (size_t)NE * NH;     // 8192 halves per plane
    const size_t wneed = (4 * nW14 + 4 * nW23) * sizeof(_Float16);

    if (d_ws != nullptr && ws_size >= wneed) {
        _Float16* w1thi = (_Float16*)d_ws;
        _Float16* w1tlo = w1thi + nW14;
        _Float16* w4thi = w1tlo + nW14;
        _Float16* w4tlo = w4thi + nW14;
        _Float16* w2thi = w4tlo + nW14;
        _Float16* w2tlo = w2thi + nW23;
        _Float16* w3thi = w2tlo + nW23;
        _Float16* w3tlo = w3thi + nW23;

        prep4_kernel<<<NBW1 + NBW4 + NBW2 + NBW3, 256, 0, stream>>>(
            W1, w1thi, w1tlo, W4, w4thi, w4tlo,
            W2, w2thi, w2tlo, W3, w3thi, w3tlo);

        mega_kernel<<<NB / 32, 1024, 0, stream>>>(
            x, reps, w1thi, w1tlo, w2thi, w2tlo, w3thi, w3tlo, w4thi, w4tlo,
            b1, b2, b3, b4, emb, recon, dist, wout);
    } else {
        // Fallback: original serialized 5-launch path with output-aliased
        // scratch (safe because launches are ordered).
        float* h = dist;
        _Float16* h2hi  = (_Float16*)(dist + (size_t)NB * NH);
        _Float16* h2lo  = h2hi + (size_t)NB * NH;
        _Float16* w1thi = (_Float16*)wout;
        _Float16* w1tlo = w1thi + (size_t)NH * ND;
        _Float16* w4thi = w1tlo + (size_t)NH * ND;
        _Float16* w4tlo = w4thi + (size_t)ND * NH;

        splitw2_kernel<<<NH + ND, 256, 0, stream>>>(W1, w1thi, w1tlo,
                                                    W4, w4thi, w4tlo);
        mfma_gemm3<4, true, true, 2><<<dim3(128, 4), 256, 0, stream>>>(
            x, nullptr, nullptr, w1thi, w1tlo, b1, h, NH, ND, 25);
        mid_kernel<<<NB / 16, 256, 0, stream>>>(h, W2, b2, W3, b3,
                                                emb, h2hi, h2lo);
        mfma_gemm3<3, false, false, 4><<<dim3(64, 13), 256, 0, stream>>>(
            nullptr, h2hi, h2lo, w4thi, w4tlo, b4, recon, ND, NH, 8);
        dist_kernel<<<NB / 8, 512, 0, stream>>>(emb, reps, dist, wout);
    }
}

// Round 11
// 146.220 us; speedup vs baseline: 1.1117x; 1.0392x over previous
//
#include <hip/hip_runtime.h>
#include <cstddef>

// Sizes (fixed per reference): B=8192, D=784, H=256, E=32, K=512
#define NB 8192
#define ND 784
#define NH 256
#define NE 32
#define NK 512
#define ALPHA_F 1000.0f

typedef _Float16 h8 __attribute__((ext_vector_type(8)));
typedef float f32x4 __attribute__((ext_vector_type(4)));

// ---------------------------------------------------------------------------
// prep4: W [K][N] fp32 -> WT hi/lo fp16 planes [N][K], via 32x32 LDS tiles.
// ---------------------------------------------------------------------------
#define TW1 25
#define TN1 8
#define NBW1 200        // W1 784x256
#define TW4 8
#define TN4 25
#define NBW4 200        // W4 256x784
#define NBW2 8          // W2 256x32
#define NBW3 8          // W3 32x256

__global__ __launch_bounds__(256)
void prep4_kernel(const float* __restrict__ W1, _Float16* __restrict__ w1thi,
                  _Float16* __restrict__ w1tlo,
                  const float* __restrict__ W4, _Float16* __restrict__ w4thi,
                  _Float16* __restrict__ w4tlo,
                  const float* __restrict__ W2, _Float16* __restrict__ w2thi,
                  _Float16* __restrict__ w2tlo,
                  const float* __restrict__ W3, _Float16* __restrict__ w3thi,
                  _Float16* __restrict__ w3tlo) {
    __shared__ float tile[32][33];
    const int b   = blockIdx.x;
    const int tid = threadIdx.x;

    const float* W; _Float16 *hi, *lo; int K, N, kt, nt;
    if (b < NBW1) {
        W = W1; hi = w1thi; lo = w1tlo; K = ND; N = NH;
        kt = b % TW1; nt = b / TW1;
    } else if (b < NBW1 + NBW4) {
        const int bb = b - NBW1;
        W = W4; hi = w4thi; lo = w4tlo; K = NH; N = ND;
        kt = bb % TW4; nt = bb / TW4;
    } else if (b < NBW1 + NBW4 + NBW2) {
        W = W2; hi = w2thi; lo = w2tlo; K = NH; N = NE;
        kt = b - (NBW1 + NBW4); nt = 0;
    } else {
        W = W3; hi = w3thi; lo = w3tlo; K = NE; N = NH;
        kt = 0; nt = b - (NBW1 + NBW4 + NBW2);
    }
    const int k0 = kt * 32, n0 = nt * 32;
    const int row = tid >> 3, c4 = (tid & 7) * 4;
    #pragma unroll
    for (int j = 0; j < 4; ++j) {
        const int k = k0 + row, n = n0 + c4 + j;
        tile[row][c4 + j] = (k < K && n < N) ? W[(size_t)k * N + n] : 0.f;
    }
    __syncthreads();
    const int n = n0 + row;
    if (n < N) {
        #pragma unroll
        for (int j = 0; j < 4; ++j) {
            const int k = k0 + c4 + j;
            if (k < K) {
                float w = tile[c4 + j][row];
                _Float16 hh = (_Float16)w;
                float r = w - (float)hh;
                hi[(size_t)n * K + k] = hh;
                lo[(size_t)n * K + k] = (_Float16)(r * 2048.0f);
            }
        }
    }
}

// ---------------------------------------------------------------------------
// MEGA v7 = v6 + ph4 8-SLOT / 4-STEP INTERVALS (barriers 28 -> 14; single
// fp16 plane made the 8x8KB slot array fit R0) + early dist_g store (16MB
// write overlaps the min/sum reduces). Kernel is barrier-interval-bound
// (all utils low, 1 block/CU, R10) — this cuts interval count.
// 1024 threads (16 waves), conflict-free [ks][row][32] layouts.
// ---------------------------------------------------------------------------
__global__ __launch_bounds__(1024, 4)
void mega_kernel(const float* __restrict__ x, const float* __restrict__ reps,
                 const _Float16* __restrict__ w1thi, const _Float16* __restrict__ w1tlo,
                 const _Float16* __restrict__ w2thi, const _Float16* __restrict__ w2tlo,
                 const _Float16* __restrict__ w3thi, const _Float16* __restrict__ w3tlo,
                 const _Float16* __restrict__ w4thi, const _Float16* __restrict__ w4tlo,
                 const float* __restrict__ b1, const float* __restrict__ b2,
                 const float* __restrict__ b3, const float* __restrict__ b4,
                 float* __restrict__ emb_g, float* __restrict__ recon_g,
                 float* __restrict__ dist_g, float* __restrict__ wout_g) {
    // LDS map (bytes):
    // [0,66560)       R0: ph1 sB dbuf (64KB) | ph2 W2 | ph3 W3hi |
    //                 ph4 sB 8-slot [8][4096]h (64KB) |
    //                 ph5 tr0 [16][520]f @0 + tr1 @33280
    // [66560,74752)   sA dbuf [2][1024]h x2
    // [74752,107520)  h planes x2 (ph1-2) / h2 single plane (ph3-4)
    // [107520,112128) es f32 [32][36]
    // [112128,116224) emb planes [32][32]h x2
    // [116224,116480) rmin[32], rinv[32]
    __shared__ __align__(16) unsigned char lds[116480];
    _Float16* R0h  = (_Float16*)lds;
    _Float16* sA   = (_Float16*)(lds + 66560);
    _Float16* hP   = (_Float16*)(lds + 74752);
    float*    es   = (float*)(lds + 107520);
    _Float16* eP   = (_Float16*)(lds + 112128);
    float*    rmin = (float*)(lds + 116224);
    float*    rinv = (float*)(lds + 116352);

    const int tid  = threadIdx.x;
    const int lane = tid & 63;
    const int wv   = tid >> 6;          // 0..15
    const int li   = lane & 15;
    const int kq   = (lane >> 4) * 8;
    const int quad = lane >> 4;
    const int r0   = blockIdx.x * 32;

    const float c1 = 1.0f / 2048.0f;
    const float c2 = c1 * c1;

    // ---------------- phase 1: h planes = split(relu(x @ W1 + b1)) ----------
    {
        _Float16* sBhi = R0h;                   // [2][8192]
        _Float16* sBlo = R0h + 2 * 8192;
        _Float16* sAhi = sA;                    // [2][1024]
        _Float16* sAlo = sA + 2 * 1024;
        const int aro  = tid >> 2;              // A: tid<128 -> rows 0..31
        const int ak   = (tid & 3) * 8;
        const int brow = tid >> 2;              // B: 0..255
        const int bk   = (tid & 3) * 8;
        const float*    pA  = x + (size_t)(r0 + aro) * ND;
        const _Float16* pBh = w1thi + (size_t)brow * ND;
        const _Float16* pBl = w1tlo + (size_t)brow * ND;

        float araw[8];
        h8 rbh, rbl;

        auto pf = [&](int s) {
            if (tid < 128) {
                const int k = s * 32 + ak;
                if (k + 8 <= ND) {
                    f32x4 v0 = *(const f32x4*)(pA + k);
                    f32x4 v1 = *(const f32x4*)(pA + k + 4);
                    #pragma unroll
                    for (int j = 0; j < 4; ++j) {
                        araw[j] = v0[j]; araw[4 + j] = v1[j];
                    }
                } else {
                    #pragma unroll
                    for (int j = 0; j < 8; ++j) araw[j] = 0.f;
                }
            }
            const int kb = s * 32 + bk;
            rbh = (kb + 8 <= ND) ? *(const h8*)(pBh + kb) : (h8){};
            rbl = (kb + 8 <= ND) ? *(const h8*)(pBl + kb) : (h8){};
        };
        auto cm = [&](int buf) {
            if (tid < 128) {
                h8 hi, lo;
                #pragma unroll
                for (int j = 0; j < 8; ++j) {
                    float v = araw[j];
                    _Float16 hh = (_Float16)v;
                    hi[j] = hh;
                    lo[j] = (_Float16)((v - (float)hh) * 2048.0f);
                }
                *(h8*)&sAhi[buf * 1024 + aro * 32 + ak] = hi;   // 16*tid contig
                *(h8*)&sAlo[buf * 1024 + aro * 32 + ak] = lo;
            }
            *(h8*)&sBhi[buf * 8192 + brow * 32 + bk] = rbh;     // 16*tid contig
            *(h8*)&sBlo[buf * 8192 + brow * 32 + bk] = rbl;
        };

        pf(0); cm(0); pf(1);
        __syncthreads();

        f32x4 a0[2] = {}, a1[2] = {}, a2[2] = {};
        for (int s = 0; s < 25; ++s) {
            const int buf = s & 1;
            h8 fah[2], fal[2];
            #pragma unroll
            for (int mt = 0; mt < 2; ++mt) {
                const int ao = buf * 1024 + (mt * 16 + li) * 32 + kq;  // contig 1KB
                fah[mt] = *(const h8*)&sAhi[ao];
                fal[mt] = *(const h8*)&sAlo[ao];
            }
            const int bo = buf * 8192 + (wv * 16 + li) * 32 + kq;      // contig 1KB
            h8 fbh = *(const h8*)&sBhi[bo];
            h8 fbl = *(const h8*)&sBlo[bo];
            #pragma unroll
            for (int mt = 0; mt < 2; ++mt) {
                a0[mt] = __builtin_amdgcn_mfma_f32_16x16x32_f16(fah[mt], fbh, a0[mt], 0, 0, 0);
                a1[mt] = __builtin_amdgcn_mfma_f32_16x16x32_f16(fah[mt], fbl, a1[mt], 0, 0, 0);
                a1[mt] = __builtin_amdgcn_mfma_f32_16x16x32_f16(fal[mt], fbh, a1[mt], 0, 0, 0);
                a2[mt] = __builtin_amdgcn_mfma_f32_16x16x32_f16(fal[mt], fbl, a2[mt], 0, 0, 0);
            }
            if (s + 1 < 25) { cm((s + 1) & 1); if (s + 2 < 25) pf(s + 2); }
            __syncthreads();
        }
        // epilogue -> h planes [8][32][32]
        _Float16* hhi = hP;
        _Float16* hlo = hP + 8192;
        const int n  = wv * 16 + li;
        const int nb = n >> 5, nr = n & 31;
        const float bv = b1[n];
        #pragma unroll
        for (int mt = 0; mt < 2; ++mt)
            #pragma unroll
            for (int r = 0; r < 4; ++r) {
                const int m = mt * 16 + quad * 4 + r;
                float v = a0[mt][r] + c1 * a1[mt][r] + c2 * a2[mt][r] + bv;
                v = fmaxf(v, 0.f);
                _Float16 t = (_Float16)v;
                hhi[nb * 1024 + m * 32 + nr] = t;
                hlo[nb * 1024 + m * 32 + nr] = (_Float16)((v - (float)t) * 2048.0f);
            }
    }
    __syncthreads();

    // ---------------- phase 2: emb = h @ W2 + b2 (full split, critical) -----
    {   // stage W2T planes [32 col][256 k] -> LDS [8 ks][32 col][32]
        _Float16* w2h = R0h;                    // [8192]
        _Float16* w2l = R0h + 8192;
        const int col = tid >> 5;               // 0..31
        const int k8  = tid & 31;               // h8 chunk 0..31
        const int src = col * 256 + k8 * 8;
        const int dst = (k8 >> 2) * 1024 + col * 32 + (k8 & 3) * 8;
        *(h8*)&w2h[dst] = *(const h8*)(w2thi + src);
        *(h8*)&w2l[dst] = *(const h8*)(w2tlo + src);
    }
    __syncthreads();
    if (wv < 4) {
        const int mt = wv >> 1, nt = wv & 1;
        _Float16* hhi = hP;
        _Float16* hlo = hP + 8192;
        _Float16* w2h = R0h;
        _Float16* w2l = R0h + 8192;
        f32x4 e0 = {}, e1 = {}, e2 = {};
        #pragma unroll
        for (int ks = 0; ks < 8; ++ks) {
            h8 ah = *(const h8*)&hhi[ks * 1024 + (mt * 16 + li) * 32 + kq];
            h8 al = *(const h8*)&hlo[ks * 1024 + (mt * 16 + li) * 32 + kq];
            h8 bh = *(const h8*)&w2h[ks * 1024 + (nt * 16 + li) * 32 + kq];
            h8 bl = *(const h8*)&w2l[ks * 1024 + (nt * 16 + li) * 32 + kq];
            e0 = __builtin_amdgcn_mfma_f32_16x16x32_f16(ah, bh, e0, 0, 0, 0);
            e1 = __builtin_amdgcn_mfma_f32_16x16x32_f16(ah, bl, e1, 0, 0, 0);
            e1 = __builtin_amdgcn_mfma_f32_16x16x32_f16(al, bh, e1, 0, 0, 0);
            e2 = __builtin_amdgcn_mfma_f32_16x16x32_f16(al, bl, e2, 0, 0, 0);
        }
        const int col = nt * 16 + li;
        const float bv = b2[col];
        _Float16* eh = eP;                      // [32][32]
        _Float16* el = eP + 1024;
        #pragma unroll
        for (int r = 0; r < 4; ++r) {
            const int m = mt * 16 + quad * 4 + r;
            float v = e0[r] + c1 * e1[r] + c2 * e2[r] + bv;
            es[m * 36 + col] = v;
            _Float16 t = (_Float16)v;
            eh[m * 32 + col] = t;
            el[m * 32 + col] = (_Float16)((v - (float)t) * 2048.0f);
            emb_g[(size_t)(r0 + m) * NE + col] = v;
        }
    }
    __syncthreads();

    // ---------------- phase 3: h2 = relu(emb @ W3 + b3), plain fp16 ---------
    {   // stage W3T hi plane only [256][32] (contiguous copy: 1024 chunks)
        _Float16* w3h = R0h;
        const int o = tid * 8;
        *(h8*)&w3h[o] = *(const h8*)(w3thi + o);
    }
    __syncthreads();
    {
        _Float16* w3h  = R0h;
        _Float16* h2h  = hP;                    // SINGLE plane (overlays h)
        _Float16* eh   = eP;
        h8 ah[2];
        #pragma unroll
        for (int mt = 0; mt < 2; ++mt)
            ah[mt] = *(const h8*)&eh[(mt * 16 + li) * 32 + kq];
        const int col = wv * 16 + li;
        h8 bh = *(const h8*)&w3h[col * 32 + kq];
        const float bv = b3[col];
        const int cb = col >> 5, cr = col & 31;
        #pragma unroll
        for (int mt = 0; mt < 2; ++mt) {
            f32x4 q0 = {};
            q0 = __builtin_amdgcn_mfma_f32_16x16x32_f16(ah[mt], bh, q0, 0, 0, 0);
            #pragma unroll
            for (int r = 0; r < 4; ++r) {
                const int m = mt * 16 + quad * 4 + r;
                float v = q0[r] + bv;
                v = fmaxf(v, 0.f);
                h2h[cb * 1024 + m * 32 + cr] = (_Float16)v;
            }
        }
    }
    __syncthreads();

    // ---------------- phase 4: recon = h2 @ W4 + b4, 8-slot / 4-step --------
    {
        _Float16* sBhi = R0h;                   // [8][4096] single plane, 64KB
        _Float16* h2h  = hP;
        const int mt  = wv >> 3;                // 0..1 (row half)
        const int ntw = wv & 7;                 // 0..7 (col group)
        const int brow = tid >> 2;              // staging: tid<512 -> 0..127
        const int bk4  = (tid & 3) * 8;
        h8 rbh[4];                              // reg slots by step&3
        auto pf = [&](int ss) {
            if (tid < 512 && ss < 56) {
                int rg = (ss >> 3) * 128 + brow;
                if (rg > ND - 1) rg = ND - 1;
                const int k = (ss & 7) * 32 + bk4;
                rbh[ss & 3] = *(const h8*)(w4thi + (size_t)rg * NH + k);
            }
        };
        auto cm = [&](int ss) {
            if (tid < 512 && ss < 56) {
                const int sl = ss & 7;
                *(h8*)&sBhi[sl * 4096 + brow * 32 + bk4] = rbh[ss & 3];
            }
        };
        pf(0); pf(1); pf(2); pf(3);
        cm(0); cm(1); cm(2); cm(3);
        pf(4); pf(5); pf(6); pf(7);
        __syncthreads();

        f32x4 q0 = {};
        auto step = [&](int t) {
            const int sl = t & 7, ks = t & 7;
            const int bo = sl * 4096 + (ntw * 16 + li) * 32 + kq;      // contig
            h8 fbh = *(const h8*)&sBhi[bo];
            const int ao = ks * 1024 + (mt * 16 + li) * 32 + kq;       // contig
            h8 ah = *(const h8*)&h2h[ao];
            q0 = __builtin_amdgcn_mfma_f32_16x16x32_f16(ah, fbh, q0, 0, 0, 0);
            if (ks == 7) {
                const int n = (t >> 3) * 128 + ntw * 16 + li;
                if (n < ND) {
                    const float bv = b4[n];
                    #pragma unroll
                    for (int r = 0; r < 4; ++r) {
                        const int m = mt * 16 + quad * 4 + r;
                        recon_g[(size_t)(r0 + m) * ND + n] = q0[r] + bv;
                    }
                }
                q0 = {};
            }
        };
        for (int ii = 0; ii < 14; ++ii) {
            const int s0 = ii * 4;
            step(s0); step(s0 + 1); step(s0 + 2); step(s0 + 3);
            cm(s0 + 4); cm(s0 + 5); cm(s0 + 6); cm(s0 + 7);  // slots (s0+4..7)&7
            pf(s0 + 8); pf(s0 + 9); pf(s0 + 10); pf(s0 + 11);
            __syncthreads();
        }
    }
    __syncthreads();

    // ---------------- phase 5: distances + stable softmin -------------------
    {
        float* tr0 = (float*)lds;               // [16][520] rows 0-15
        float* tr1 = (float*)(lds + 33280);     // [16][520] rows 16-31
        const int half = tid >> 9;              // 0: rows 0-15, 1: rows 16-31
        const int cl   = tid & 511;             // cluster id
        float* trh = half ? tr1 : tr0;
        const int rbase = half * 16;

        const float* rp = reps + (size_t)cl * NE;
        f32x4 rv[8];
        #pragma unroll
        for (int e4 = 0; e4 < 8; ++e4) rv[e4] = ((const f32x4*)rp)[e4];

        float d[16];
        #pragma unroll
        for (int r = 0; r < 16; ++r) {
            float a = 0.f;
            #pragma unroll
            for (int e4 = 0; e4 < 8; ++e4) {
                f32x4 ev = *(const f32x4*)&es[(rbase + r) * 36 + e4 * 4];  // broadcast
                #pragma unroll
                for (int j = 0; j < 4; ++j) {
                    float t = ev[j] - rv[e4][j];
                    a = fmaf(t, t, a);
                }
            }
            d[r] = a;
            trh[r * 520 + cl] = a;
            dist_g[(size_t)(r0 + rbase + r) * NK + cl] = a;   // early: overlaps reduces
        }
        __syncthreads();
        {   // min-reduce: wave handles 2 rows of its half; stride-64 scalar
            const int w8 = wv & 7;
            #pragma unroll
            for (int p = 0; p < 2; ++p) {
                const int rl = w8 * 2 + p;
                float m = trh[rl * 520 + lane];
                #pragma unroll
                for (int j = 1; j < 8; ++j)
                    m = fminf(m, trh[rl * 520 + lane + 64 * j]);
                #pragma unroll
                for (int off = 32; off > 0; off >>= 1)
                    m = fminf(m, __shfl_xor(m, off, 64));
                if (lane == 0) rmin[rbase + rl] = m;
            }
        }
        __syncthreads();
        #pragma unroll
        for (int r = 0; r < 16; ++r)
            trh[r * 520 + cl] = expf(-ALPHA_F * (d[r] - rmin[rbase + r]));
        __syncthreads();
        {   // sum-reduce
            const int w8 = wv & 7;
            #pragma unroll
            for (int p = 0; p < 2; ++p) {
                const int rl = w8 * 2 + p;
                float s = trh[rl * 520 + lane];
                #pragma unroll
                for (int j = 1; j < 8; ++j)
                    s += trh[rl * 520 + lane + 64 * j];
                #pragma unroll
                for (int off = 32; off > 0; off >>= 1)
                    s += __shfl_xor(s, off, 64);
                if (lane == 0) rinv[rbase + rl] = 1.0f / s;
            }
        }
        __syncthreads();
        #pragma unroll
        for (int r = 0; r < 16; ++r) {
            const size_t row = (size_t)(r0 + rbase + r);
            const float ev = trh[r * 520 + cl];      // exps still live in LDS
            wout_g[row * NK + cl] = d[r] * (ev * rinv[rbase + r]);
        }
    }
}

// ===========================================================================
// Fallback path (no/insufficient workspace): original verified 5-launch chain.
// ===========================================================================
__global__ __launch_bounds__(256)
void splitw2_kernel(const float* __restrict__ W1, _Float16* __restrict__ w1thi,
                    _Float16* __restrict__ w1tlo,
                    const float* __restrict__ W4, _Float16* __restrict__ w4thi,
                    _Float16* __restrict__ w4tlo) {
    const int b = blockIdx.x;
    const float* W; _Float16 *hi, *lo; int K, N, n;
    if (b < NH) { W = W1; hi = w1thi; lo = w1tlo; K = ND; N = NH; n = b; }
    else        { W = W4; hi = w4thi; lo = w4tlo; K = NH; N = ND; n = b - NH; }
    for (int k = threadIdx.x; k < K; k += 256) {
        float w = W[(size_t)k * N + n];
        _Float16 hh = (_Float16)w;
        float r = w - (float)hh;
        hi[(size_t)n * K + k] = hh;
        lo[(size_t)n * K + k] = (_Float16)(r * 2048.0f);
    }
}

template<int TERMS, bool RELU, bool SPLITA, int MT>
__global__ __launch_bounds__(256)
void mfma_gemm3(const float* __restrict__ Af32,
                const _Float16* __restrict__ Ahi_g,
                const _Float16* __restrict__ Alo_g,
                const _Float16* __restrict__ WThi,
                const _Float16* __restrict__ WTlo,
                const float* __restrict__ bias, float* __restrict__ C,
                int N, int K, int KS) {
    constexpr int BM  = MT * 32;
    constexpr int ACH = BM / 64;
    constexpr int AS  = BM * 40;
    constexpr int BS  = 64 * 40;
    __shared__ __align__(16) _Float16 smem[2 * BM * 40 * 2 + 2 * 64 * 40 * 2];
    _Float16* sAhi = smem;
    _Float16* sAlo = sAhi + 2 * BM * 40;
    _Float16* sBhi = sAlo + 2 * BM * 40;
    _Float16* sBlo = sBhi + 2 * 64 * 40;

    const int tid = threadIdx.x;
    const int bm  = blockIdx.x * BM;
    const int bn  = blockIdx.y * 64;

    const int arow = (ACH == 1) ? (tid >> 2) : (tid >> 1);
    const int ak   = (ACH == 1) ? ((tid & 3) * 8) : ((tid & 1) * 16);
    const int brow = tid >> 2;
    const int bk   = (tid & 3) * 8;

    const float*    pA32 = SPLITA ? Af32 + (size_t)(bm + arow) * K : nullptr;
    const _Float16* pAhi = SPLITA ? nullptr : Ahi_g + (size_t)(bm + arow) * K;
    const _Float16* pAlo = SPLITA ? nullptr : Alo_g + (size_t)(bm + arow) * K;
    int brow_g = bn + brow; if (brow_g > N - 1) brow_g = N - 1;
    const _Float16* pBhi = WThi + (size_t)brow_g * K;
    const _Float16* pBlo = WTlo + (size_t)brow_g * K;

    float araw[ACH * 8];
    h8 rahi[ACH], ralo[ACH];
    h8 rbhi, rblo;

    auto prefetch = [&](int s) {
        #pragma unroll
        for (int c = 0; c < ACH; ++c) {
            const int k = s * 32 + ak + c * 8;
            if (SPLITA) {
                if (k + 8 <= K) {
                    f32x4 v0 = *(const f32x4*)(pA32 + k);
                    f32x4 v1 = *(const f32x4*)(pA32 + k + 4);
                    #pragma unroll
                    for (int j = 0; j < 4; ++j) {
                        araw[c * 8 + j]     = v0[j];
                        araw[c * 8 + 4 + j] = v1[j];
                    }
                } else {
                    #pragma unroll
                    for (int j = 0; j < 8; ++j) araw[c * 8 + j] = 0.f;
                }
            } else {
                rahi[c] = (k + 8 <= K) ? *(const h8*)(pAhi + k) : (h8){};
                ralo[c] = (k + 8 <= K) ? *(const h8*)(pAlo + k) : (h8){};
            }
        }
        const int kb = s * 32 + bk;
        rbhi = (kb + 8 <= K) ? *(const h8*)(pBhi + kb) : (h8){};
        rblo = (kb + 8 <= K) ? *(const h8*)(pBlo + kb) : (h8){};
    };

    auto commit = [&](int buf) {
        #pragma unroll
        for (int c = 0; c < ACH; ++c) {
            h8 hi, lo;
            if (SPLITA) {
                #pragma unroll
                for (int j = 0; j < 8; ++j) {
                    float v = araw[c * 8 + j];
                    _Float16 hh = (_Float16)v;
                    hi[j] = hh;
                    lo[j] = (_Float16)((v - (float)hh) * 2048.0f);
                }
            } else { hi = rahi[c]; lo = ralo[c]; }
            *(h8*)&sAhi[buf * AS + arow * 40 + ak + c * 8] = hi;
            *(h8*)&sAlo[buf * AS + arow * 40 + ak + c * 8] = lo;
        }
        *(h8*)&sBhi[buf * BS + brow * 40 + bk] = rbhi;
        *(h8*)&sBlo[buf * BS + brow * 40 + bk] = rblo;
    };

    prefetch(0);
    commit(0);
    prefetch(1);
    __syncthreads();

    const int lane = tid & 63;
    const int wv   = tid >> 6;
    const int wm   = (wv >> 1) * (MT * 16);
    const int wn   = (wv & 1) * 32;
    const int li   = lane & 15;
    const int kq   = (lane >> 4) * 8;

    f32x4 acc0[MT][2] = {};
    f32x4 acc1[MT][2] = {};
    f32x4 acc2[MT][2] = {};

    for (int s = 0; s < KS; ++s) {
        const int buf = s & 1;
        h8 fahi[MT], falo[MT], fbhi[2], fblo[2];
        #pragma unroll
        for (int mt = 0; mt < MT; ++mt) {
            const int ao = buf * AS + (wm + mt * 16 + li) * 40 + kq;
            fahi[mt] = *(const h8*)&sAhi[ao];
            falo[mt] = *(const h8*)&sAlo[ao];
        }
        #pragma unroll
        for (int nt = 0; nt < 2; ++nt) {
            const int bo = buf * BS + (wn + nt * 16 + li) * 40 + kq;
            fbhi[nt] = *(const h8*)&sBhi[bo];
            fblo[nt] = *(const h8*)&sBlo[bo];
        }
        #pragma unroll
        for (int mt = 0; mt < MT; ++mt)
            #pragma unroll
            for (int nt = 0; nt < 2; ++nt) {
                acc0[mt][nt] = __builtin_amdgcn_mfma_f32_16x16x32_f16(
                    fahi[mt], fbhi[nt], acc0[mt][nt], 0, 0, 0);
                acc1[mt][nt] = __builtin_amdgcn_mfma_f32_16x16x32_f16(
                    fahi[mt], fblo[nt], acc1[mt][nt], 0, 0, 0);
                acc1[mt][nt] = __builtin_amdgcn_mfma_f32_16x16x32_f16(
                    falo[mt], fbhi[nt], acc1[mt][nt], 0, 0, 0);
                if (TERMS == 4)
                    acc2[mt][nt] = __builtin_amdgcn_mfma_f32_16x16x32_f16(
                        falo[mt], fblo[nt], acc2[mt][nt], 0, 0, 0);
            }
        if (s + 1 < KS) {
            commit((s + 1) & 1);
            if (s + 2 < KS) prefetch(s + 2);
        }
        __syncthreads();
    }

    const float c1 = 1.0f / 2048.0f;
    const float c2 = c1 * c1;
    const int quad = lane >> 4;
    #pragma unroll
    for (int nt = 0; nt < 2; ++nt) {
        const int n = bn + wn + nt * 16 + li;
        if (n < N) {
            const float bv = bias[n];
            #pragma unroll
            for (int mt = 0; mt < MT; ++mt) {
                #pragma unroll
                for (int r = 0; r < 4; ++r) {
                    const int m = bm + wm + mt * 16 + quad * 4 + r;
                    float v = acc0[mt][nt][r] + c1 * acc1[mt][nt][r];
                    if (TERMS == 4) v += c2 * acc2[mt][nt][r];
                    v += bv;
                    if (RELU) v = fmaxf(v, 0.f);
                    C[(size_t)m * N + n] = v;
                }
            }
        }
    }
}

__global__ __launch_bounds__(256)
void mid_kernel(const float* __restrict__ h, const float* __restrict__ W2,
                const float* __restrict__ b2, const float* __restrict__ W3,
                const float* __restrict__ b3, float* __restrict__ emb,
                _Float16* __restrict__ h2hi, _Float16* __restrict__ h2lo) {
    __shared__ float es[16][32];
    const int tid = threadIdx.x;
    const int r0  = blockIdx.x * 16;

    #pragma unroll
    for (int half = 0; half < 2; ++half) {
        const int o   = tid + half * 256;
        const int row = o >> 5;
        const int col = o & 31;
        const float* hrow = h + (size_t)(r0 + row) * NH;
        float acc0 = 0.f, acc1 = 0.f;
        #pragma unroll 4
        for (int k = 0; k < NH; k += 4) {
            float4 hv = *(const float4*)(hrow + k);
            acc0 = fmaf(hv.x, W2[(k + 0) * NE + col], acc0);
            acc1 = fmaf(hv.y, W2[(k + 1) * NE + col], acc1);
            acc0 = fmaf(hv.z, W2[(k + 2) * NE + col], acc0);
            acc1 = fmaf(hv.w, W2[(k + 3) * NE + col], acc1);
        }
        float v = acc0 + acc1 + b2[col];
        es[row][col] = v;
        emb[(size_t)r0 * NE + o] = v;
    }
    __syncthreads();

    const int col = tid;
    float acc[16];
    #pragma unroll
    for (int r = 0; r < 16; ++r) acc[r] = 0.f;
    #pragma unroll
    for (int k = 0; k < NE; ++k) {
        float w = W3[k * NH + col];
        #pragma unroll
        for (int r = 0; r < 16; ++r) acc[r] = fmaf(es[r][k], w, acc[r]);
    }
    const float bb = b3[col];
    #pragma unroll
    for (int r = 0; r < 16; ++r) {
        float v = acc[r] + bb;
        v = v > 0.f ? v : 0.f;
        _Float16 hh = (_Float16)v;
        float rr = v - (float)hh;
        h2hi[(size_t)(r0 + r) * NH + col] = hh;
        h2lo[(size_t)(r0 + r) * NH + col] = (_Float16)(rr * 2048.0f);
    }
}

__global__ __launch_bounds__(512, 4)
void dist_kernel(const float* __restrict__ emb, const float* __restrict__ reps,
                 float* __restrict__ dist, float* __restrict__ wout) {
    __shared__ float es[8][32];
    __shared__ float tr[8][520];
    __shared__ float rmin[8];
    __shared__ float rinv[8];

    const int tid = threadIdx.x;
    const int r0  = blockIdx.x * 8;

    if (tid < 256) es[tid >> 5][tid & 31] = emb[(size_t)r0 * NE + tid];

    const float* rp = reps + (size_t)tid * NE;
    f32x4 rv[8];
    #pragma unroll
    for (int e4 = 0; e4 < 8; ++e4) rv[e4] = ((const f32x4*)rp)[e4];
    __syncthreads();

    float d[8];
    #pragma unroll
    for (int r = 0; r < 8; ++r) {
        float a = 0.f;
        #pragma unroll
        for (int e4 = 0; e4 < 8; ++e4) {
            f32x4 ev = *(const f32x4*)&es[r][e4 * 4];
            #pragma unroll
            for (int j = 0; j < 4; ++j) {
                float t = ev[j] - rv[e4][j];
                a = fmaf(t, t, a);
            }
        }
        d[r] = a;
    }

    const int lane = tid & 63;
    const int wv   = tid >> 6;

    #pragma unroll
    for (int r = 0; r < 8; ++r) tr[r][tid] = d[r];
    __syncthreads();
    {
        f32x4 a = *(const f32x4*)&tr[wv][lane * 8];
        f32x4 b = *(const f32x4*)&tr[wv][lane * 8 + 4];
        float m = fminf(fminf(fminf(a[0], a[1]), fminf(a[2], a[3])),
                        fminf(fminf(b[0], b[1]), fminf(b[2], b[3])));
        #pragma unroll
        for (int off = 32; off > 0; off >>= 1)
            m = fminf(m, __shfl_xor(m, off, 64));
        if (lane == 0) rmin[wv] = m;
    }
    __syncthreads();

    float e[8];
    #pragma unroll
    for (int r = 0; r < 8; ++r) {
        e[r] = expf(-ALPHA_F * (d[r] - rmin[r]));
        tr[r][tid] = e[r];
    }
    __syncthreads();
    {
        f32x4 a = *(const f32x4*)&tr[wv][lane * 8];
        f32x4 b = *(const f32x4*)&tr[wv][lane * 8 + 4];
        float s = ((a[0] + a[1]) + (a[2] + a[3])) +
                  ((b[0] + b[1]) + (b[2] + b[3]));
        #pragma unroll
        for (int off = 32; off > 0; off >>= 1)
            s += __shfl_xor(s, off, 64);
        if (lane == 0) rinv[wv] = 1.0f / s;
    }
    __syncthreads();

    #pragma unroll
    for (int r = 0; r < 8; ++r) {
        const size_t row = (size_t)(r0 + r);
        dist[row * NK + tid] = d[r];
        wout[row * NK + tid] = d[r] * (e[r] * rinv[r]);
    }
}

// ---------------------------------------------------------------------------
extern "C" void kernel_launch(void* const* d_in, const int* in_sizes, int n_in,
                              void* d_out, int out_size, void* d_ws, size_t ws_size,
                              hipStream_t stream) {
    const float* x    = (const float*)d_in[0];
    const float* reps = (const float*)d_in[1];
    const float* W1   = (const float*)d_in[2];
    const float* b1   = (const float*)d_in[3];
    const float* W2   = (const float*)d_in[4];
    const float* b2   = (const float*)d_in[5];
    const float* W3   = (const float*)d_in[6];
    const float* b3   = (const float*)d_in[7];
    const float* W4   = (const float*)d_in[8];
    const float* b4   = (const float*)d_in[9];

    float* out   = (float*)d_out;
    float* wout  = out;                                          // [8192,512]
    float* dist  = out + (size_t)NB * NK;                        // [8192,512]
    float* recon = out + (size_t)2 * NB * NK;                    // [8192,784]
    float* emb   = out + (size_t)2 * NB * NK + (size_t)NB * ND;  // [8192,32]

    // Workspace: weight planes only (~1.7 MB): W1T, W4T, W2T, W3T hi/lo.
    const size_t nW14 = (size_t)ND * NH;     // 200704 halves per plane
    const size_t nW23 = (size_t)NE * NH;     // 8192 halves per plane
    const size_t wneed = (4 * nW14 + 4 * nW23) * sizeof(_Float16);

    if (d_ws != nullptr && ws_size >= wneed) {
        _Float16* w1thi = (_Float16*)d_ws;
        _Float16* w1tlo = w1thi + nW14;
        _Float16* w4thi = w1tlo + nW14;
        _Float16* w4tlo = w4thi + nW14;
        _Float16* w2thi = w4tlo + nW14;
        _Float16* w2tlo = w2thi + nW23;
        _Float16* w3thi = w2tlo + nW23;
        _Float16* w3tlo = w3thi + nW23;

        prep4_kernel<<<NBW1 + NBW4 + NBW2 + NBW3, 256, 0, stream>>>(
            W1, w1thi, w1tlo, W4, w4thi, w4tlo,
            W2, w2thi, w2tlo, W3, w3thi, w3tlo);

        mega_kernel<<<NB / 32, 1024, 0, stream>>>(
            x, reps, w1thi, w1tlo, w2thi, w2tlo, w3thi, w3tlo, w4thi, w4tlo,
            b1, b2, b3, b4, emb, recon, dist, wout);
    } else {
        // Fallback: original serialized 5-launch path with output-aliased
        // scratch (safe because launches are ordered).
        float* h = dist;
        _Float16* h2hi  = (_Float16*)(dist + (size_t)NB * NH);
        _Float16* h2lo  = h2hi + (size_t)NB * NH;
        _Float16* w1thi = (_Float16*)wout;
        _Float16* w1tlo = w1thi + (size_t)NH * ND;
        _Float16* w4thi = w1tlo + (size_t)NH * ND;
        _Float16* w4tlo = w4thi + (size_t)ND * NH;

        splitw2_kernel<<<NH + ND, 256, 0, stream>>>(W1, w1thi, w1tlo,
                                                    W4, w4thi, w4tlo);
        mfma_gemm3<4, true, true, 2><<<dim3(128, 4), 256, 0, stream>>>(
            x, nullptr, nullptr, w1thi, w1tlo, b1, h, NH, ND, 25);
        mid_kernel<<<NB / 16, 256, 0, stream>>>(h, W2, b2, W3, b3,
                                                emb, h2hi, h2lo);
        mfma_gemm3<3, false, false, 4><<<dim3(64, 13), 256, 0, stream>>>(
            nullptr, h2hi, h2lo, w4thi, w4tlo, b4, recon, ND, NH, 8);
        dist_kernel<<<NB / 8, 512, 0, stream>>>(emb, reps, dist, wout);
    }
}